// Round 1
// baseline (1562.147 us; speedup 1.0000x reference)
//
#include <hip/hip_runtime.h>
#include <math.h>

#define Bn 256
#define Tn 256

__constant__ int EB[32] = {0,3,5,8,10,13,15,18,22,25,29,33,38,42,48,53,59,66,73,80,89,97,107,117,128,140,153,167,183,199,216,256};

__device__ __forceinline__ float sig(float x){ return 1.f/(1.f + expf(-x)); }

// ---------------- K1: stage1 fc_in: x0[t,b,h] = b[h] + sum_i x[b,t,i]*W[h,i]
// x[b,t,2f+0] = main[b,0,t-1,f] (0 if t==0), x[b,t,2f+1] = main[b,0,t,f]
__global__ __launch_bounds__(256) void k1(const float* __restrict__ mi,
                                          const float* __restrict__ w,
                                          const float* __restrict__ bias,
                                          float* __restrict__ x0){
  int gid = blockIdx.x*256 + threadIdx.x;       // (t*Bn + b)*32 + h
  int h = gid & 31;
  int b = (gid >> 5) & 255;
  int t = gid >> 13;
  const float* wr = w + h*64;
  const float* mc = mi + (b*Tn + t)*32;
  float s = bias[h];
  #pragma unroll
  for (int f = 0; f < 32; ++f){
    float cur  = mc[f];
    float prev = (t > 0) ? mc[f - 32] : 0.f;
    s = fmaf(prev, wr[2*f],   s);
    s = fmaf(cur,  wr[2*f+1], s);
  }
  x0[gid] = s;
}

// ---------------- K2: stage1 GRU0 -> GRU1 -> x1=y1+y2 -> band_mask = sig(x1 @ fco)
// thread = (row in block [2 rows], h [32], q [4]); q splits K=32 into 8-slices.
__global__ __launch_bounds__(256) void k2(const float* __restrict__ x0,
    const float* __restrict__ wih0, const float* __restrict__ whh0,
    const float* __restrict__ bih0, const float* __restrict__ bhh0,
    const float* __restrict__ wih1, const float* __restrict__ whh1,
    const float* __restrict__ bih1, const float* __restrict__ bhh1,
    const float* __restrict__ fco,
    float* __restrict__ bmA, float* __restrict__ bmB)
{
  const int tid = threadIdx.x;
  const int row = tid >> 7;
  const int h   = (tid >> 2) & 31;
  const int q   = tid & 3;
  const int b   = blockIdx.x*2 + row;

  float a0i[3][8], a0h[3][8], a1i[3][8], a1h[3][8], afc[8];
  #pragma unroll
  for (int g = 0; g < 3; ++g){
    const int r_ = (g*32 + h)*32 + q*8;
    #pragma unroll
    for (int k = 0; k < 8; ++k){
      a0i[g][k] = wih0[r_ + k];
      a0h[g][k] = whh0[r_ + k];
      a1i[g][k] = wih1[r_ + k];
      a1h[g][k] = whh1[r_ + k];
    }
  }
  const float b0r  = bih0[h]      + bhh0[h];
  const float b0z  = bih0[32+h]   + bhh0[32+h];
  const float b0in = bih0[64+h];
  const float b0hn = bhh0[64+h];
  const float b1r  = bih1[h]      + bhh1[h];
  const float b1z  = bih1[32+h]   + bhh1[32+h];
  const float b1in = bih1[64+h];
  const float b1hn = bhh1[64+h];
  #pragma unroll
  for (int k = 0; k < 8; ++k) afc[k] = fco[(q*8+k)*32 + h];

  __shared__ __attribute__((aligned(16))) float h1[2][32];
  __shared__ __attribute__((aligned(16))) float h2[2][32];
  __shared__ __attribute__((aligned(16))) float x1b[2][32];
  if (tid < 64){ ((float*)h1)[tid] = 0.f; ((float*)h2)[tid] = 0.f; }
  __syncthreads();

  for (int t = 0; t < Tn; ++t){
    float xv[8], hv[8];
    const float* xp = x0 + (t*Bn + b)*32 + q*8;
    ((float4*)xv)[0] = ((const float4*)xp)[0];
    ((float4*)xv)[1] = ((const float4*)xp)[1];
    ((float4*)hv)[0] = *(const float4*)&h1[row][q*8];
    ((float4*)hv)[1] = *(const float4*)&h1[row][q*8+4];
    float pr=0.f, pz=0.f, pi=0.f, ph=0.f;
    #pragma unroll
    for (int k = 0; k < 8; ++k){
      pr = fmaf(xv[k], a0i[0][k], pr); pr = fmaf(hv[k], a0h[0][k], pr);
      pz = fmaf(xv[k], a0i[1][k], pz); pz = fmaf(hv[k], a0h[1][k], pz);
      pi = fmaf(xv[k], a0i[2][k], pi);
      ph = fmaf(hv[k], a0h[2][k], ph);
    }
    pr += __shfl_xor(pr,1); pr += __shfl_xor(pr,2);
    pz += __shfl_xor(pz,1); pz += __shfl_xor(pz,2);
    pi += __shfl_xor(pi,1); pi += __shfl_xor(pi,2);
    ph += __shfl_xor(ph,1); ph += __shfl_xor(ph,2);
    float hold = h1[row][h];
    float r = sig(pr + b0r);
    float z = sig(pz + b0z);
    float n = tanhf(pi + b0in + r*(ph + b0hn));
    float hn1 = (1.f - z)*n + z*hold;
    __syncthreads();
    if (q == 0) h1[row][h] = hn1;
    __syncthreads();
    // GRU2 (input = y1 = updated h1)
    ((float4*)xv)[0] = *(const float4*)&h1[row][q*8];
    ((float4*)xv)[1] = *(const float4*)&h1[row][q*8+4];
    ((float4*)hv)[0] = *(const float4*)&h2[row][q*8];
    ((float4*)hv)[1] = *(const float4*)&h2[row][q*8+4];
    pr=0.f; pz=0.f; pi=0.f; ph=0.f;
    #pragma unroll
    for (int k = 0; k < 8; ++k){
      pr = fmaf(xv[k], a1i[0][k], pr); pr = fmaf(hv[k], a1h[0][k], pr);
      pz = fmaf(xv[k], a1i[1][k], pz); pz = fmaf(hv[k], a1h[1][k], pz);
      pi = fmaf(xv[k], a1i[2][k], pi);
      ph = fmaf(hv[k], a1h[2][k], ph);
    }
    pr += __shfl_xor(pr,1); pr += __shfl_xor(pr,2);
    pz += __shfl_xor(pz,1); pz += __shfl_xor(pz,2);
    pi += __shfl_xor(pi,1); pi += __shfl_xor(pi,2);
    ph += __shfl_xor(ph,1); ph += __shfl_xor(ph,2);
    float hold2 = h2[row][h];
    r = sig(pr + b1r);
    z = sig(pz + b1z);
    n = tanhf(pi + b1in + r*(ph + b1hn));
    float hn2 = (1.f - z)*n + z*hold2;
    __syncthreads();
    if (q == 0){ h2[row][h] = hn2; x1b[row][h] = hn1 + hn2; }
    __syncthreads();
    // fcout -> band_mask
    float x1v[8];
    ((float4*)x1v)[0] = *(const float4*)&x1b[row][q*8];
    ((float4*)x1v)[1] = *(const float4*)&x1b[row][q*8+4];
    float s = 0.f;
    #pragma unroll
    for (int k = 0; k < 8; ++k) s = fmaf(x1v[k], afc[k], s);
    s += __shfl_xor(s,1); s += __shfl_xor(s,2);
    float bm = sig(s);
    if (q == 0){
      bmA[(b*Tn + t)*32 + h] = bm;      // [B,T,32]
      bmB[(b*32 + h)*Tn + t] = bm;      // [B,32,T]
    }
  }
}

// ---------------- K3: full_mask[b,f,t] = bm[i]*(1-fr) + bm[i+1]*fr  (f=256 -> 0)
__global__ __launch_bounds__(256) void k3(const float* __restrict__ bmB,
                                          float* __restrict__ out0){
  int f = blockIdx.x % 257;
  int b = blockIdx.x / 257;
  int t = threadIdx.x;
  float full = 0.f;
  if (f < 256){
    int i = 0;
    #pragma unroll
    for (int k = 1; k < 31; ++k) if (f >= EB[k]) i = k;
    float fr = (float)(f - EB[i]) / (float)(EB[i+1] - EB[i]);
    full = bmB[(b*32 + i)*Tn + t]*(1.f - fr) + bmB[(b*32 + i + 1)*Tn + t]*fr;
  }
  out0[(b*257 + f)*Tn + t] = full;
}

// ---------------- K4: low/high fc_in + PReLU. 24 threads per (b,t): 16 low-quads + 8 high-quads.
__global__ __launch_bounds__(192) void k4(const float* __restrict__ lpi,
    const float* __restrict__ bmA,
    const float* __restrict__ wlo, const float* __restrict__ plo,
    const float* __restrict__ whi, const float* __restrict__ phi,
    float* __restrict__ lowx, float* __restrict__ highx)
{
  int tid = threadIdx.x;
  int pair = tid / 24;
  int c = tid - pair*24;
  int bt = blockIdx.x*8 + pair;
  int b = bt >> 8, t = bt & 255;
  const float* lrow = lpi + (b*Tn + t)*256;
  const float* brow = bmA + (b*Tn + t)*32;
  if (c < 16){
    float4 p = {0.f,0.f,0.f,0.f};
    for (int i = 0; i < 128; ++i){
      float v = lrow[i];
      float4 wv = *(const float4*)&wlo[i*64 + c*4];
      p.x = fmaf(v, wv.x, p.x); p.y = fmaf(v, wv.y, p.y);
      p.z = fmaf(v, wv.z, p.z); p.w = fmaf(v, wv.w, p.w);
    }
    for (int i = 0; i < 32; ++i){
      float v = brow[i];
      float4 wv = *(const float4*)&wlo[(128+i)*64 + c*4];
      p.x = fmaf(v, wv.x, p.x); p.y = fmaf(v, wv.y, p.y);
      p.z = fmaf(v, wv.z, p.z); p.w = fmaf(v, wv.w, p.w);
    }
    float a = plo[0];
    p.x = p.x >= 0.f ? p.x : a*p.x;
    p.y = p.y >= 0.f ? p.y : a*p.y;
    p.z = p.z >= 0.f ? p.z : a*p.z;
    p.w = p.w >= 0.f ? p.w : a*p.w;
    *(float4*)&lowx[(t*Bn + b)*64 + c*4] = p;
  } else {
    int c2 = c - 16;
    int g = c2 >> 2;
    int oo = (c2 & 3)*4;
    float4 p = {0.f,0.f,0.f,0.f};
    for (int i = 0; i < 80; ++i){
      int idx = g*80 + i;
      float v = (idx < 128) ? lrow[128 + idx] : brow[idx - 128];
      float4 wv = *(const float4*)&whi[(g*80 + i)*16 + oo];
      p.x = fmaf(v, wv.x, p.x); p.y = fmaf(v, wv.y, p.y);
      p.z = fmaf(v, wv.z, p.z); p.w = fmaf(v, wv.w, p.w);
    }
    float a = phi[0];
    p.x = p.x >= 0.f ? p.x : a*p.x;
    p.y = p.y >= 0.f ? p.y : a*p.y;
    p.z = p.z >= 0.f ? p.z : a*p.z;
    p.w = p.w >= 0.f ? p.w : a*p.w;
    *(float4*)&highx[(t*Bn + b)*32 + g*16 + oo] = p;
  }
}

// ---------------- K5: low grouped 2-layer GRU with channel shuffle; acc = shuffle(y0)+y1
// block = 1 batch row; thread = (g[2], h[32], q[4])
__global__ __launch_bounds__(256) void k5(const float* __restrict__ lowx,
    const float* __restrict__ wih, const float* __restrict__ whh,
    const float* __restrict__ bih, const float* __restrict__ bhh,
    float* __restrict__ acc)
{
  const int tid = threadIdx.x;
  const int g = tid >> 7;
  const int h = (tid >> 2) & 31;
  const int q = tid & 3;
  const int b = blockIdx.x;

  float a0i[3][8], a0h[3][8], a1i[3][8], a1h[3][8];
  #pragma unroll
  for (int gate = 0; gate < 3; ++gate){
    const int r0 = ((g)*96   + gate*32 + h)*32 + q*8;   // layer0
    const int r1 = ((2+g)*96 + gate*32 + h)*32 + q*8;   // layer1
    #pragma unroll
    for (int k = 0; k < 8; ++k){
      a0i[gate][k] = wih[r0 + k];
      a0h[gate][k] = whh[r0 + k];
      a1i[gate][k] = wih[r1 + k];
      a1h[gate][k] = whh[r1 + k];
    }
  }
  const float b0r  = bih[g*96 + h]      + bhh[g*96 + h];
  const float b0z  = bih[g*96 + 32 + h] + bhh[g*96 + 32 + h];
  const float b0in = bih[g*96 + 64 + h];
  const float b0hn = bhh[g*96 + 64 + h];
  const float b1r  = bih[(2+g)*96 + h]      + bhh[(2+g)*96 + h];
  const float b1z  = bih[(2+g)*96 + 32 + h] + bhh[(2+g)*96 + 32 + h];
  const float b1in = bih[(2+g)*96 + 64 + h];
  const float b1hn = bhh[(2+g)*96 + 64 + h];

  __shared__ __attribute__((aligned(16))) float h0[2][32];
  __shared__ __attribute__((aligned(16))) float h1s[2][32];
  __shared__ __attribute__((aligned(16))) float y0[64];
  if (tid < 64){ ((float*)h0)[tid] = 0.f; ((float*)h1s)[tid] = 0.f; }
  __syncthreads();

  for (int t = 0; t < Tn; ++t){
    float xv[8], hv[8];
    const float* xp = lowx + (t*Bn + b)*64 + g*32 + q*8;
    ((float4*)xv)[0] = ((const float4*)xp)[0];
    ((float4*)xv)[1] = ((const float4*)xp)[1];
    ((float4*)hv)[0] = *(const float4*)&h0[g][q*8];
    ((float4*)hv)[1] = *(const float4*)&h0[g][q*8+4];
    float pr=0.f, pz=0.f, pi=0.f, ph=0.f;
    #pragma unroll
    for (int k = 0; k < 8; ++k){
      pr = fmaf(xv[k], a0i[0][k], pr); pr = fmaf(hv[k], a0h[0][k], pr);
      pz = fmaf(xv[k], a0i[1][k], pz); pz = fmaf(hv[k], a0h[1][k], pz);
      pi = fmaf(xv[k], a0i[2][k], pi);
      ph = fmaf(hv[k], a0h[2][k], ph);
    }
    pr += __shfl_xor(pr,1); pr += __shfl_xor(pr,2);
    pz += __shfl_xor(pz,1); pz += __shfl_xor(pz,2);
    pi += __shfl_xor(pi,1); pi += __shfl_xor(pi,2);
    ph += __shfl_xor(ph,1); ph += __shfl_xor(ph,2);
    float hold = h0[g][h];
    float r = sig(pr + b0r);
    float z = sig(pz + b0z);
    float n = tanhf(pi + b0in + r*(ph + b0hn));
    float hn0 = (1.f - z)*n + z*hold;
    __syncthreads();
    if (q == 0){ h0[g][h] = hn0; y0[g*32 + h] = hn0; }
    __syncthreads();
    // layer1: input = shuffled y0: in[c] = y0[(c&31)*2 + (c>>5)], c = g*32+q*8+k
    float xv1[8];
    #pragma unroll
    for (int k = 0; k < 8; ++k) xv1[k] = y0[((q*8+k)<<1) | g];
    ((float4*)hv)[0] = *(const float4*)&h1s[g][q*8];
    ((float4*)hv)[1] = *(const float4*)&h1s[g][q*8+4];
    pr=0.f; pz=0.f; pi=0.f; ph=0.f;
    #pragma unroll
    for (int k = 0; k < 8; ++k){
      pr = fmaf(xv1[k], a1i[0][k], pr); pr = fmaf(hv[k], a1h[0][k], pr);
      pz = fmaf(xv1[k], a1i[1][k], pz); pz = fmaf(hv[k], a1h[1][k], pz);
      pi = fmaf(xv1[k], a1i[2][k], pi);
      ph = fmaf(hv[k], a1h[2][k], ph);
    }
    pr += __shfl_xor(pr,1); pr += __shfl_xor(pr,2);
    pz += __shfl_xor(pz,1); pz += __shfl_xor(pz,2);
    pi += __shfl_xor(pi,1); pi += __shfl_xor(pi,2);
    ph += __shfl_xor(ph,1); ph += __shfl_xor(ph,2);
    float hold1 = h1s[g][h];
    r = sig(pr + b1r);
    z = sig(pz + b1z);
    n = tanhf(pi + b1in + r*(ph + b1hn));
    float hn1 = (1.f - z)*n + z*hold1;
    float sh = y0[(h << 1) | g];
    __syncthreads();
    if (q == 0){ h1s[g][h] = hn1; acc[(t*Bn + b)*64 + g*32 + h] = sh + hn1; }
  }
}

// ---------------- K6: high grouped GRU (g=2, H=16). thread = (row[2], g[2], h[16], q[4])
__global__ __launch_bounds__(256) void k6(const float* __restrict__ highx,
    const float* __restrict__ wih, const float* __restrict__ whh,
    const float* __restrict__ bih, const float* __restrict__ bhh,
    float* __restrict__ dfh)
{
  const int tid = threadIdx.x;
  const int r_ = tid >> 7;
  const int g  = (tid >> 6) & 1;
  const int h  = (tid >> 2) & 15;
  const int q  = tid & 3;
  const int b  = blockIdx.x*2 + r_;
  float ai[3][4], ah[3][4];
  #pragma unroll
  for (int gate = 0; gate < 3; ++gate){
    const int base = (g*48 + gate*16 + h)*16 + q*4;
    #pragma unroll
    for (int k = 0; k < 4; ++k){ ai[gate][k] = wih[base + k]; ah[gate][k] = whh[base + k]; }
  }
  const float br_  = bih[g*48 + h]      + bhh[g*48 + h];
  const float bz_  = bih[g*48 + 16 + h] + bhh[g*48 + 16 + h];
  const float bin_ = bih[g*48 + 32 + h];
  const float bhn_ = bhh[g*48 + 32 + h];
  __shared__ __attribute__((aligned(16))) float hh[2][2][16];
  if (tid < 64) ((float*)hh)[tid] = 0.f;
  __syncthreads();
  for (int t = 0; t < Tn; ++t){
    float4 xv = *(const float4*)(highx + (t*Bn + b)*32 + g*16 + q*4);
    float4 hv = *(const float4*)&hh[r_][g][q*4];
    float pr=0.f, pz=0.f, pi=0.f, ph=0.f;
    pr = fmaf(xv.x, ai[0][0], pr); pr = fmaf(xv.y, ai[0][1], pr); pr = fmaf(xv.z, ai[0][2], pr); pr = fmaf(xv.w, ai[0][3], pr);
    pr = fmaf(hv.x, ah[0][0], pr); pr = fmaf(hv.y, ah[0][1], pr); pr = fmaf(hv.z, ah[0][2], pr); pr = fmaf(hv.w, ah[0][3], pr);
    pz = fmaf(xv.x, ai[1][0], pz); pz = fmaf(xv.y, ai[1][1], pz); pz = fmaf(xv.z, ai[1][2], pz); pz = fmaf(xv.w, ai[1][3], pz);
    pz = fmaf(hv.x, ah[1][0], pz); pz = fmaf(hv.y, ah[1][1], pz); pz = fmaf(hv.z, ah[1][2], pz); pz = fmaf(hv.w, ah[1][3], pz);
    pi = fmaf(xv.x, ai[2][0], pi); pi = fmaf(xv.y, ai[2][1], pi); pi = fmaf(xv.z, ai[2][2], pi); pi = fmaf(xv.w, ai[2][3], pi);
    ph = fmaf(hv.x, ah[2][0], ph); ph = fmaf(hv.y, ah[2][1], ph); ph = fmaf(hv.z, ah[2][2], ph); ph = fmaf(hv.w, ah[2][3], ph);
    pr += __shfl_xor(pr,1); pr += __shfl_xor(pr,2);
    pz += __shfl_xor(pz,1); pz += __shfl_xor(pz,2);
    pi += __shfl_xor(pi,1); pi += __shfl_xor(pi,2);
    ph += __shfl_xor(ph,1); ph += __shfl_xor(ph,2);
    float hold = hh[r_][g][h];
    float r = sig(pr + br_);
    float z = sig(pz + bz_);
    float n = tanhf(pi + bin_ + r*(ph + bhn_));
    float hn = (1.f - z)*n + z*hold;
    __syncthreads();
    if (q == 0){ hh[r_][g][h] = hn; dfh[(t*Bn + b)*32 + g*16 + h] = hn; }
    __syncthreads();
  }
}

// ---------------- K7: fused mask_low/high fc + final mask/mag/spec_out fusion.
// block = (b, t-tile of 32); 256 threads = 32 tl x 8 fo (16 f each)
__global__ __launch_bounds__(256) void k7(const float* __restrict__ acc,
    const float* __restrict__ dfh,
    const float* __restrict__ wlo, const float* __restrict__ whi,
    const float* __restrict__ spec,
    float* __restrict__ out)
{
  __shared__ float accs[32][65];
  __shared__ float dfhs[32][33];
  __shared__ float mlds[128][32];
  __shared__ float mhds[128][32];
  const int tid = threadIdx.x;
  const int b  = blockIdx.x >> 3;
  const int t0 = (blockIdx.x & 7) * 32;
  for (int idx = tid; idx < 32*16; idx += 256){
    int tl = idx >> 4, c4 = (idx & 15)*4;
    float4 v = *(const float4*)&acc[((t0 + tl)*Bn + b)*64 + c4];
    accs[tl][c4] = v.x; accs[tl][c4+1] = v.y; accs[tl][c4+2] = v.z; accs[tl][c4+3] = v.w;
  }
  for (int idx = tid; idx < 32*8; idx += 256){
    int tl = idx >> 3, c4 = (idx & 7)*4;
    float4 v = *(const float4*)&dfh[((t0 + tl)*Bn + b)*32 + c4];
    dfhs[tl][c4] = v.x; dfhs[tl][c4+1] = v.y; dfhs[tl][c4+2] = v.z; dfhs[tl][c4+3] = v.w;
  }
  __syncthreads();
  const int tl = tid & 31, fo = tid >> 5;   // fo in 0..7
  {
    float p[16];
    #pragma unroll
    for (int j = 0; j < 16; ++j) p[j] = 0.f;
    for (int i = 0; i < 64; ++i){
      float a = accs[tl][i];
      const float4* wr = (const float4*)&wlo[i*128 + fo*16];
      #pragma unroll
      for (int j4 = 0; j4 < 4; ++j4){
        float4 wv = wr[j4];
        p[j4*4+0] = fmaf(a, wv.x, p[j4*4+0]);
        p[j4*4+1] = fmaf(a, wv.y, p[j4*4+1]);
        p[j4*4+2] = fmaf(a, wv.z, p[j4*4+2]);
        p[j4*4+3] = fmaf(a, wv.w, p[j4*4+3]);
      }
    }
    #pragma unroll
    for (int j = 0; j < 16; ++j) mlds[fo*16 + j][tl] = sig(p[j]);
  }
  {
    float p[16];
    #pragma unroll
    for (int j = 0; j < 16; ++j) p[j] = 0.f;
    const int g = fo >> 2, ob = (fo & 3)*16;
    for (int i = 0; i < 16; ++i){
      float a = dfhs[tl][g*16 + i];
      const float4* wr = (const float4*)&whi[(g*16 + i)*64 + ob];
      #pragma unroll
      for (int j4 = 0; j4 < 4; ++j4){
        float4 wv = wr[j4];
        p[j4*4+0] = fmaf(a, wv.x, p[j4*4+0]);
        p[j4*4+1] = fmaf(a, wv.y, p[j4*4+1]);
        p[j4*4+2] = fmaf(a, wv.z, p[j4*4+2]);
        p[j4*4+3] = fmaf(a, wv.w, p[j4*4+3]);
      }
    }
    #pragma unroll
    for (int j = 0; j < 16; ++j) mhds[fo*16 + j][tl] = sig(p[j]);
  }
  __syncthreads();
  float* out1 = out + 16842752;
  float* out2 = out + 2*16842752;
  float2* out3 = (float2*)(out + 3*16842752);
  const float2* sp2 = (const float2*)spec;
  for (int f = fo; f < 257; f += 8){
    int base = (b*257 + f)*Tn + t0 + tl;
    float full = out[base];
    float m = (f < 128) ? mlds[f][tl]*full
            : (f < 256 ? mhds[f-128][tl]*full : full);
    float2 s = sp2[base];
    float ox = s.x*full, oy = s.y*full;
    float sx = ox*m, sy = oy*m;
    out1[base] = m;
    out2[base] = sqrtf(sx*sx + sy*sy);
    out3[base] = make_float2(sx, sy);
  }
}

extern "C" void kernel_launch(void* const* d_in, const int* in_sizes, int n_in,
                              void* d_out, int out_size, void* d_ws, size_t ws_size,
                              hipStream_t stream){
  const float* mi   = (const float*)d_in[0];
  const float* spec = (const float*)d_in[1];
  const float* lpi  = (const float*)d_in[2];
  const float* s1w  = (const float*)d_in[5];
  const float* s1b  = (const float*)d_in[6];
  const float* wih0 = (const float*)d_in[7];
  const float* whh0 = (const float*)d_in[8];
  const float* bih0 = (const float*)d_in[9];
  const float* bhh0 = (const float*)d_in[10];
  const float* wih1 = (const float*)d_in[11];
  const float* whh1 = (const float*)d_in[12];
  const float* bih1 = (const float*)d_in[13];
  const float* bhh1 = (const float*)d_in[14];
  const float* fco  = (const float*)d_in[15];
  const float* filw = (const float*)d_in[16];
  const float* plo  = (const float*)d_in[17];
  const float* fihw = (const float*)d_in[18];
  const float* phi  = (const float*)d_in[19];
  const float* glw_ih = (const float*)d_in[20];
  const float* glw_hh = (const float*)d_in[21];
  const float* glb_ih = (const float*)d_in[22];
  const float* glb_hh = (const float*)d_in[23];
  const float* ghw_ih = (const float*)d_in[24];
  const float* ghw_hh = (const float*)d_in[25];
  const float* ghb_ih = (const float*)d_in[26];
  const float* ghb_hh = (const float*)d_in[27];
  const float* folw = (const float*)d_in[28];
  const float* fohw = (const float*)d_in[29];

  float* ws    = (float*)d_ws;
  float* x0    = ws;                  // [T,B,32]  2,097,152
  float* bmA   = ws + 2097152;        // [B,T,32]  2,097,152
  float* bmB   = ws + 4194304;        // [B,32,T]  2,097,152
  float* lowx  = ws + 6291456;        // [T,B,64]  4,194,304
  float* highx = ws + 10485760;       // [T,B,32]  2,097,152
  float* acc   = ws + 12582912;       // [T,B,64]  4,194,304
  float* dfh   = ws + 16777216;       // [T,B,32]  2,097,152
  float* out   = (float*)d_out;

  k1<<<8192, 256, 0, stream>>>(mi, s1w, s1b, x0);
  k2<<<128, 256, 0, stream>>>(x0, wih0, whh0, bih0, bhh0,
                              wih1, whh1, bih1, bhh1, fco, bmA, bmB);
  k3<<<256*257, 256, 0, stream>>>(bmB, out);
  k4<<<8192, 192, 0, stream>>>(lpi, bmA, filw, plo, fihw, phi, lowx, highx);
  k5<<<256, 256, 0, stream>>>(lowx, glw_ih, glw_hh, glb_ih, glb_hh, acc);
  k6<<<128, 256, 0, stream>>>(highx, ghw_ih, ghw_hh, ghb_ih, ghb_hh, dfh);
  k7<<<2048, 256, 0, stream>>>(acc, dfh, folw, fohw, spec, out);
}

// Round 2
// 1537.697 us; speedup vs baseline: 1.0159x; 1.0159x over previous
//
#include <hip/hip_runtime.h>
#include <math.h>

#define Bn 256
#define Tn 256

__constant__ int EB[32] = {0,3,5,8,10,13,15,18,22,25,29,33,38,42,48,53,59,66,73,80,89,97,107,117,128,140,153,167,183,199,216,256};

__device__ __forceinline__ float sigf(float x){ return __fdividef(1.f, 1.f + __expf(-x)); }
__device__ __forceinline__ float thf(float x){ return 1.f - __fdividef(2.f, __expf(2.f*x) + 1.f); }

// ---------- k0: collapse fc_in into GRU0 input weights: wc[96][64] = wih0 @ wfc, bc = wih0@bfc + bih0
__global__ __launch_bounds__(256) void k0(const float* __restrict__ wfc, const float* __restrict__ bfc,
                                          const float* __restrict__ wih0, const float* __restrict__ bih0,
                                          float* __restrict__ wc, float* __restrict__ bc){
  int i = blockIdx.x*256 + threadIdx.x;
  if (i < 6144){
    int o = i >> 6, c = i & 63;
    float s = 0.f;
    #pragma unroll
    for (int k = 0; k < 32; ++k) s = fmaf(wih0[o*32+k], wfc[k*64+c], s);
    wc[i] = s;
  }
  if (i < 96){
    float s = bih0[i];
    #pragma unroll
    for (int k = 0; k < 32; ++k) s = fmaf(wih0[i*32+k], bfc[k], s);
    bc[i] = s;
  }
}

// ---------- k1: Gi0[t][b][96] = x(b,t) @ wc^T + bc   (x built from mi prev/cur interleave)
__global__ __launch_bounds__(256) void k1(const float* __restrict__ mi,
                                          const float* __restrict__ wc, const float* __restrict__ bc,
                                          float* __restrict__ gi0){
  int idx = blockIdx.x*256 + threadIdx.x;       // (t*Bn+b)*96 + o
  int o = idx % 96; int bt = idx / 96;
  int b = bt & 255, t = bt >> 8;
  const float4* w4 = (const float4*)(wc + o*64);
  const float* mc = mi + (b*Tn + t)*32;
  const float4* cur4 = (const float4*)mc;
  const float4* prv4 = (const float4*)(mc - 32);
  float s = bc[o];
  #pragma unroll
  for (int j = 0; j < 8; ++j){
    float4 c = cur4[j];
    float4 p = make_float4(0.f,0.f,0.f,0.f);
    if (t > 0) p = prv4[j];
    float4 wa = w4[2*j], wb = w4[2*j+1];
    s = fmaf(p.x, wa.x, s); s = fmaf(c.x, wa.y, s);
    s = fmaf(p.y, wa.z, s); s = fmaf(c.y, wa.w, s);
    s = fmaf(p.z, wb.x, s); s = fmaf(c.z, wb.y, s);
    s = fmaf(p.w, wb.z, s); s = fmaf(c.w, wb.w, s);
  }
  gi0[idx] = s;
}

// ---------- k2: stage1 double GRU + band-mask fc. One wave per batch. lane = q*32+h.
__global__ __launch_bounds__(64) void k2(const float* __restrict__ gi0,
    const float* __restrict__ whh0, const float* __restrict__ bhh0,
    const float* __restrict__ wih1, const float* __restrict__ whh1,
    const float* __restrict__ bih1, const float* __restrict__ bhh1,
    const float* __restrict__ fco, float* __restrict__ bmA)
{
  const int lane = threadIdx.x;
  const int q = lane >> 5, h = lane & 31, ko = q*16;
  const int b = blockIdx.x;
  float a0h[3][16], a1i[3][16], a1h[3][16], afc[16];
  #pragma unroll
  for (int g = 0; g < 3; ++g){
    const float* w0 = whh0 + (g*32+h)*32 + ko;
    const float* wi = wih1 + (g*32+h)*32 + ko;
    const float* wh = whh1 + (g*32+h)*32 + ko;
    #pragma unroll
    for (int k = 0; k < 16; ++k){ a0h[g][k]=w0[k]; a1i[g][k]=wi[k]; a1h[g][k]=wh[k]; }
  }
  #pragma unroll
  for (int k = 0; k < 16; ++k) afc[k] = fco[(ko+k)*32 + h];
  const float bh0r = bhh0[h], bh0z = bhh0[32+h], bh0n = bhh0[64+h];
  const float b1r = bih1[h] + bhh1[h], b1z = bih1[32+h] + bhh1[32+h];
  const float bi1n = bih1[64+h], bh1n = bhh1[64+h];

  float h1own = 0.f, h2own = 0.f;
  float h1v[16], h2v[16];
  #pragma unroll
  for (int k = 0; k < 16; ++k){ h1v[k]=0.f; h2v[k]=0.f; }

  const float* gA = gi0 + b*96;
  const float* gB = gi0 + (Bn + b)*96;
  float c_r = gA[h], c_z = gA[32+h], c_n = gA[64+h];
  float n1r = gB[h], n1z = gB[32+h], n1n = gB[64+h];

  for (int t = 0; t < Tn; ++t){
    int tp = (t+2 < Tn) ? t+2 : Tn-1;
    const float* gC = gi0 + (tp*Bn + b)*96;
    float n2r = gC[h], n2z = gC[32+h], n2n = gC[64+h];
    // GRU0 (recurrent part only)
    float pr = 0.f, pz = 0.f, pn = 0.f;
    #pragma unroll
    for (int k = 0; k < 16; ++k){
      pr = fmaf(h1v[k], a0h[0][k], pr);
      pz = fmaf(h1v[k], a0h[1][k], pz);
      pn = fmaf(h1v[k], a0h[2][k], pn);
    }
    pr += __shfl_xor(pr, 32);
    pz += __shfl_xor(pz, 32);
    pn += __shfl_xor(pn, 32);
    float r = sigf(c_r + pr + bh0r);
    float z = sigf(c_z + pz + bh0z);
    float nn = thf(c_n + r*(pn + bh0n));
    float hn1 = nn + z*(h1own - nn);
    h1own = hn1;
    #pragma unroll
    for (int k = 0; k < 16; ++k) h1v[k] = __shfl(hn1, ko + k);
    // GRU1 (full, input = y1 = h1 new)
    float qr = 0.f, qz = 0.f, qi = 0.f, qh = 0.f;
    #pragma unroll
    for (int k = 0; k < 16; ++k){
      qr = fmaf(h1v[k], a1i[0][k], qr); qr = fmaf(h2v[k], a1h[0][k], qr);
      qz = fmaf(h1v[k], a1i[1][k], qz); qz = fmaf(h2v[k], a1h[1][k], qz);
      qi = fmaf(h1v[k], a1i[2][k], qi);
      qh = fmaf(h2v[k], a1h[2][k], qh);
    }
    qr += __shfl_xor(qr, 32);
    qz += __shfl_xor(qz, 32);
    qi += __shfl_xor(qi, 32);
    qh += __shfl_xor(qh, 32);
    float r1 = sigf(qr + b1r);
    float z1 = sigf(qz + b1z);
    float n1 = thf(qi + bi1n + r1*(qh + bh1n));
    float hn2 = n1 + z1*(h2own - n1);
    h2own = hn2;
    #pragma unroll
    for (int k = 0; k < 16; ++k) h2v[k] = __shfl(hn2, ko + k);
    // fc -> band mask
    float s = 0.f;
    #pragma unroll
    for (int k = 0; k < 16; ++k) s = fmaf(h1v[k] + h2v[k], afc[k], s);
    s += __shfl_xor(s, 32);
    if (q == 0) bmA[(b*Tn + t)*32 + h] = sigf(s);
    c_r = n1r; c_z = n1z; c_n = n1n;
    n1r = n2r; n1z = n2z; n1n = n2n;
  }
}

// ---------- k4: low/high fc_in + PReLU (unchanged from passing version)
__global__ __launch_bounds__(192) void k4(const float* __restrict__ lpi,
    const float* __restrict__ bmA,
    const float* __restrict__ wlo, const float* __restrict__ plo,
    const float* __restrict__ whi, const float* __restrict__ phi,
    float* __restrict__ lowx, float* __restrict__ highx)
{
  int tid = threadIdx.x;
  int pair = tid / 24;
  int c = tid - pair*24;
  int bt = blockIdx.x*8 + pair;
  int b = bt >> 8, t = bt & 255;
  const float* lrow = lpi + (b*Tn + t)*256;
  const float* brow = bmA + (b*Tn + t)*32;
  if (c < 16){
    float4 p = {0.f,0.f,0.f,0.f};
    for (int i = 0; i < 128; ++i){
      float v = lrow[i];
      float4 wv = *(const float4*)&wlo[i*64 + c*4];
      p.x = fmaf(v, wv.x, p.x); p.y = fmaf(v, wv.y, p.y);
      p.z = fmaf(v, wv.z, p.z); p.w = fmaf(v, wv.w, p.w);
    }
    for (int i = 0; i < 32; ++i){
      float v = brow[i];
      float4 wv = *(const float4*)&wlo[(128+i)*64 + c*4];
      p.x = fmaf(v, wv.x, p.x); p.y = fmaf(v, wv.y, p.y);
      p.z = fmaf(v, wv.z, p.z); p.w = fmaf(v, wv.w, p.w);
    }
    float a = plo[0];
    p.x = p.x >= 0.f ? p.x : a*p.x;
    p.y = p.y >= 0.f ? p.y : a*p.y;
    p.z = p.z >= 0.f ? p.z : a*p.z;
    p.w = p.w >= 0.f ? p.w : a*p.w;
    *(float4*)&lowx[(t*Bn + b)*64 + c*4] = p;
  } else {
    int c2 = c - 16;
    int g = c2 >> 2;
    int oo = (c2 & 3)*4;
    float4 p = {0.f,0.f,0.f,0.f};
    for (int i = 0; i < 80; ++i){
      int idx = g*80 + i;
      float v = (idx < 128) ? lrow[128 + idx] : brow[idx - 128];
      float4 wv = *(const float4*)&whi[(g*80 + i)*16 + oo];
      p.x = fmaf(v, wv.x, p.x); p.y = fmaf(v, wv.y, p.y);
      p.z = fmaf(v, wv.z, p.z); p.w = fmaf(v, wv.w, p.w);
    }
    float a = phi[0];
    p.x = p.x >= 0.f ? p.x : a*p.x;
    p.y = p.y >= 0.f ? p.y : a*p.y;
    p.z = p.z >= 0.f ? p.z : a*p.z;
    p.w = p.w >= 0.f ? p.w : a*p.w;
    *(float4*)&highx[(t*Bn + b)*32 + g*16 + oo] = p;
  }
}

// ---------- k4b: GiL[t][b][192] = lowx_g @ WihL0_g^T + bihL0_g
__global__ __launch_bounds__(256) void k4b(const float* __restrict__ lowx,
    const float* __restrict__ wih, const float* __restrict__ bih,
    float* __restrict__ giL){
  int idx = blockIdx.x*256 + threadIdx.x;     // bt*192 + o
  int o = idx % 192; int bt = idx / 192;
  int g = o / 96, r = o - g*96;
  const float4* x4 = (const float4*)(lowx + bt*64 + g*32);
  const float4* w4 = (const float4*)(wih + (g*96 + r)*32);
  float s = bih[g*96 + r];
  #pragma unroll
  for (int j = 0; j < 8; ++j){
    float4 a = x4[j], w = w4[j];
    s = fmaf(a.x, w.x, s); s = fmaf(a.y, w.y, s);
    s = fmaf(a.z, w.z, s); s = fmaf(a.w, w.w, s);
  }
  giL[idx] = s;
}

// ---------- k4c: GiH[t][b][96] = highx_g @ WihH_g^T + bihH_g
__global__ __launch_bounds__(256) void k4c(const float* __restrict__ highx,
    const float* __restrict__ wih, const float* __restrict__ bih,
    float* __restrict__ giH){
  int idx = blockIdx.x*256 + threadIdx.x;     // bt*96 + o
  int o = idx % 96; int bt = idx / 96;
  int g = o / 48, r = o - g*48;
  const float4* x4 = (const float4*)(highx + bt*32 + g*16);
  const float4* w4 = (const float4*)(wih + (g*48 + r)*16);
  float s = bih[g*48 + r];
  #pragma unroll
  for (int j = 0; j < 4; ++j){
    float4 a = x4[j], w = w4[j];
    s = fmaf(a.x, w.x, s); s = fmaf(a.y, w.y, s);
    s = fmaf(a.z, w.z, s); s = fmaf(a.w, w.w, s);
  }
  giH[idx] = s;
}

// ---------- k5: low grouped 2-layer GRU + shuffle. 2 waves per batch (wave = group).
__global__ __launch_bounds__(128) void k5(const float* __restrict__ giL,
    const float* __restrict__ wih, const float* __restrict__ whh,
    const float* __restrict__ bih, const float* __restrict__ bhh,
    float* __restrict__ acc)
{
  const int tid = threadIdx.x;
  const int g = tid >> 6;
  const int lane = tid & 63;
  const int q = lane >> 5, h = lane & 31, ko = q*16;
  const int b = blockIdx.x;
  float a0h[3][16], a1i[3][16], a1h[3][16];
  #pragma unroll
  for (int gt = 0; gt < 3; ++gt){
    const float* w0 = whh + (g*96 + gt*32 + h)*32 + ko;
    const float* wi = wih + ((2+g)*96 + gt*32 + h)*32 + ko;
    const float* wh = whh + ((2+g)*96 + gt*32 + h)*32 + ko;
    #pragma unroll
    for (int k = 0; k < 16; ++k){ a0h[gt][k]=w0[k]; a1i[gt][k]=wi[k]; a1h[gt][k]=wh[k]; }
  }
  const float bh0r = bhh[g*96 + h], bh0z = bhh[g*96+32+h], bh0n = bhh[g*96+64+h];
  const float b1r = bih[(2+g)*96 + h] + bhh[(2+g)*96 + h];
  const float b1z = bih[(2+g)*96+32+h] + bhh[(2+g)*96+32+h];
  const float bi1n = bih[(2+g)*96+64+h], bh1n = bhh[(2+g)*96+64+h];

  __shared__ float ybuf[2][64];
  float h0own = 0.f, h1own = 0.f;
  float h0v[16], h1v[16];
  #pragma unroll
  for (int k = 0; k < 16; ++k){ h0v[k]=0.f; h1v[k]=0.f; }

  const float* gA = giL + b*192 + g*96;
  const float* gB = giL + (Bn + b)*192 + g*96;
  float c_r = gA[h], c_z = gA[32+h], c_n = gA[64+h];
  float n1r = gB[h], n1z = gB[32+h], n1n = gB[64+h];

  for (int t = 0; t < Tn; ++t){
    int tp = (t+2 < Tn) ? t+2 : Tn-1;
    const float* gC = giL + (tp*Bn + b)*192 + g*96;
    float n2r = gC[h], n2z = gC[32+h], n2n = gC[64+h];
    // layer0 recurrent
    float pr = 0.f, pz = 0.f, pn = 0.f;
    #pragma unroll
    for (int k = 0; k < 16; ++k){
      pr = fmaf(h0v[k], a0h[0][k], pr);
      pz = fmaf(h0v[k], a0h[1][k], pz);
      pn = fmaf(h0v[k], a0h[2][k], pn);
    }
    pr += __shfl_xor(pr, 32);
    pz += __shfl_xor(pz, 32);
    pn += __shfl_xor(pn, 32);
    float r = sigf(c_r + pr + bh0r);
    float z = sigf(c_z + pz + bh0z);
    float nn = thf(c_n + r*(pn + bh0n));
    float hn0 = nn + z*(h0own - nn);
    h0own = hn0;
    #pragma unroll
    for (int k = 0; k < 16; ++k) h0v[k] = __shfl(hn0, ko + k);
    // cross-group exchange, stored pre-shuffled: ybuf[c] = shuffled_y0[c]
    if (q == 0) ybuf[t&1][((h&1)<<5) + (g<<4) + (h>>1)] = hn0;
    __syncthreads();
    float xv[16];
    *(float4*)&xv[0]  = *(const float4*)&ybuf[t&1][g*32 + ko + 0];
    *(float4*)&xv[4]  = *(const float4*)&ybuf[t&1][g*32 + ko + 4];
    *(float4*)&xv[8]  = *(const float4*)&ybuf[t&1][g*32 + ko + 8];
    *(float4*)&xv[12] = *(const float4*)&ybuf[t&1][g*32 + ko + 12];
    // layer1 full
    float qr = 0.f, qz = 0.f, qi = 0.f, qh = 0.f;
    #pragma unroll
    for (int k = 0; k < 16; ++k){
      qr = fmaf(xv[k], a1i[0][k], qr); qr = fmaf(h1v[k], a1h[0][k], qr);
      qz = fmaf(xv[k], a1i[1][k], qz); qz = fmaf(h1v[k], a1h[1][k], qz);
      qi = fmaf(xv[k], a1i[2][k], qi);
      qh = fmaf(h1v[k], a1h[2][k], qh);
    }
    qr += __shfl_xor(qr, 32);
    qz += __shfl_xor(qz, 32);
    qi += __shfl_xor(qi, 32);
    qh += __shfl_xor(qh, 32);
    float r1 = sigf(qr + b1r);
    float z1 = sigf(qz + b1z);
    float n1 = thf(qi + bi1n + r1*(qh + bh1n));
    float hn1 = n1 + z1*(h1own - n1);
    h1own = hn1;
    #pragma unroll
    for (int k = 0; k < 16; ++k) h1v[k] = __shfl(hn1, ko + k);
    if (q == 0) acc[(t*Bn + b)*64 + g*32 + h] = ybuf[t&1][g*32 + h] + hn1;
    c_r = n1r; c_z = n1z; c_n = n1n;
    n1r = n2r; n1z = n2z; n1n = n2n;
  }
}

// ---------- k6: high grouped GRU (2 groups, H=16). One wave per batch. lane = g*32+q*16+h.
__global__ __launch_bounds__(64) void k6(const float* __restrict__ giH,
    const float* __restrict__ whh, const float* __restrict__ bhh,
    float* __restrict__ dfh)
{
  const int lane = threadIdx.x;
  const int g = lane >> 5, q = (lane >> 4) & 1, h = lane & 15, ko = q*8;
  const int b = blockIdx.x;
  float ah[3][8];
  #pragma unroll
  for (int gt = 0; gt < 3; ++gt){
    const float* w = whh + (g*48 + gt*16 + h)*16 + ko;
    #pragma unroll
    for (int k = 0; k < 8; ++k) ah[gt][k] = w[k];
  }
  const float bhr = bhh[g*48 + h], bhz = bhh[g*48+16+h], bhn = bhh[g*48+32+h];
  float hown = 0.f;
  float hv[8];
  #pragma unroll
  for (int k = 0; k < 8; ++k) hv[k] = 0.f;
  const float* gA = giH + b*96 + g*48;
  const float* gB = giH + (Bn + b)*96 + g*48;
  float c_r = gA[h], c_z = gA[16+h], c_n = gA[32+h];
  float n1r = gB[h], n1z = gB[16+h], n1n = gB[32+h];
  for (int t = 0; t < Tn; ++t){
    int tp = (t+2 < Tn) ? t+2 : Tn-1;
    const float* gC = giH + (tp*Bn + b)*96 + g*48;
    float n2r = gC[h], n2z = gC[16+h], n2n = gC[32+h];
    float pr = 0.f, pz = 0.f, pn = 0.f;
    #pragma unroll
    for (int k = 0; k < 8; ++k){
      pr = fmaf(hv[k], ah[0][k], pr);
      pz = fmaf(hv[k], ah[1][k], pz);
      pn = fmaf(hv[k], ah[2][k], pn);
    }
    pr += __shfl_xor(pr, 16);
    pz += __shfl_xor(pz, 16);
    pn += __shfl_xor(pn, 16);
    float r = sigf(c_r + pr + bhr);
    float z = sigf(c_z + pz + bhz);
    float nn = thf(c_n + r*(pn + bhn));
    float hn = nn + z*(hown - nn);
    hown = hn;
    #pragma unroll
    for (int k = 0; k < 8; ++k) hv[k] = __shfl(hn, g*32 + ko + k);
    if (q == 0) dfh[(t*Bn + b)*32 + g*16 + h] = hn;
    c_r = n1r; c_z = n1z; c_n = n1n;
    n1r = n2r; n1z = n2z; n1n = n2n;
  }
}

// ---------- k7: full_mask from bmA + mask_low/high fc + final fusion (k3 folded in)
__global__ __launch_bounds__(256) void k7(const float* __restrict__ acc,
    const float* __restrict__ dfh, const float* __restrict__ bmA,
    const float* __restrict__ wlo, const float* __restrict__ whi,
    const float* __restrict__ spec, float* __restrict__ out)
{
  __shared__ float accs[32][65];
  __shared__ float dfhs[32][33];
  __shared__ float bmt[32][33];
  __shared__ float mlds[128][32];
  __shared__ float mhds[128][32];
  __shared__ float frcs[257];
  __shared__ int   ibds[257];
  const int tid = threadIdx.x;
  const int b  = blockIdx.x >> 3;
  const int t0 = (blockIdx.x & 7) * 32;
  for (int idx = tid; idx < 32*16; idx += 256){
    int tl = idx >> 4, c4 = (idx & 15)*4;
    float4 v = *(const float4*)&acc[((t0 + tl)*Bn + b)*64 + c4];
    accs[tl][c4] = v.x; accs[tl][c4+1] = v.y; accs[tl][c4+2] = v.z; accs[tl][c4+3] = v.w;
  }
  for (int idx = tid; idx < 32*8; idx += 256){
    int tl = idx >> 3, c4 = (idx & 7)*4;
    float4 v = *(const float4*)&dfh[((t0 + tl)*Bn + b)*32 + c4];
    dfhs[tl][c4] = v.x; dfhs[tl][c4+1] = v.y; dfhs[tl][c4+2] = v.z; dfhs[tl][c4+3] = v.w;
    float4 u = *(const float4*)&bmA[(b*Tn + t0 + tl)*32 + c4];
    bmt[tl][c4] = u.x; bmt[tl][c4+1] = u.y; bmt[tl][c4+2] = u.z; bmt[tl][c4+3] = u.w;
  }
  for (int f = tid; f < 257; f += 256){
    int i = 0;
    #pragma unroll
    for (int k = 1; k < 31; ++k) if (f >= EB[k]) i = k;
    ibds[f] = i;
    frcs[f] = (f < 256) ? (float)(f - EB[i]) / (float)(EB[i+1] - EB[i]) : 0.f;
  }
  __syncthreads();
  const int tl = tid & 31, fo = tid >> 5;   // fo in 0..7
  {
    float p[16];
    #pragma unroll
    for (int j = 0; j < 16; ++j) p[j] = 0.f;
    for (int i = 0; i < 64; ++i){
      float a = accs[tl][i];
      const float4* wr = (const float4*)&wlo[i*128 + fo*16];
      #pragma unroll
      for (int j4 = 0; j4 < 4; ++j4){
        float4 wv = wr[j4];
        p[j4*4+0] = fmaf(a, wv.x, p[j4*4+0]);
        p[j4*4+1] = fmaf(a, wv.y, p[j4*4+1]);
        p[j4*4+2] = fmaf(a, wv.z, p[j4*4+2]);
        p[j4*4+3] = fmaf(a, wv.w, p[j4*4+3]);
      }
    }
    #pragma unroll
    for (int j = 0; j < 16; ++j) mlds[fo*16 + j][tl] = sigf(p[j]);
  }
  {
    float p[16];
    #pragma unroll
    for (int j = 0; j < 16; ++j) p[j] = 0.f;
    const int g = fo >> 2, ob = (fo & 3)*16;
    for (int i = 0; i < 16; ++i){
      float a = dfhs[tl][g*16 + i];
      const float4* wr = (const float4*)&whi[(g*16 + i)*64 + ob];
      #pragma unroll
      for (int j4 = 0; j4 < 4; ++j4){
        float4 wv = wr[j4];
        p[j4*4+0] = fmaf(a, wv.x, p[j4*4+0]);
        p[j4*4+1] = fmaf(a, wv.y, p[j4*4+1]);
        p[j4*4+2] = fmaf(a, wv.z, p[j4*4+2]);
        p[j4*4+3] = fmaf(a, wv.w, p[j4*4+3]);
      }
    }
    #pragma unroll
    for (int j = 0; j < 16; ++j) mhds[fo*16 + j][tl] = sigf(p[j]);
  }
  __syncthreads();
  float* out1 = out + 16842752;
  float* out2 = out + 2*16842752;
  float2* out3 = (float2*)(out + 3*16842752);
  const float2* sp2 = (const float2*)spec;
  for (int f = fo; f < 257; f += 8){
    int base = (b*257 + f)*Tn + t0 + tl;
    float full;
    if (f < 256){
      int i = ibds[f]; float fr = frcs[f];
      full = bmt[tl][i]*(1.f - fr) + bmt[tl][i+1]*fr;
    } else full = 0.f;
    float m = (f < 128) ? mlds[f][tl]*full
            : (f < 256 ? mhds[f-128][tl]*full : full);
    float2 s = sp2[base];
    float ox = s.x*full, oy = s.y*full;
    float sx = ox*m, sy = oy*m;
    out[base]  = full;
    out1[base] = m;
    out2[base] = sqrtf(sx*sx + sy*sy);
    out3[base] = make_float2(sx, sy);
  }
}

extern "C" void kernel_launch(void* const* d_in, const int* in_sizes, int n_in,
                              void* d_out, int out_size, void* d_ws, size_t ws_size,
                              hipStream_t stream){
  const float* mi   = (const float*)d_in[0];
  const float* spec = (const float*)d_in[1];
  const float* lpi  = (const float*)d_in[2];
  const float* s1w  = (const float*)d_in[5];
  const float* s1b  = (const float*)d_in[6];
  const float* wih0 = (const float*)d_in[7];
  const float* whh0 = (const float*)d_in[8];
  const float* bih0 = (const float*)d_in[9];
  const float* bhh0 = (const float*)d_in[10];
  const float* wih1 = (const float*)d_in[11];
  const float* whh1 = (const float*)d_in[12];
  const float* bih1 = (const float*)d_in[13];
  const float* bhh1 = (const float*)d_in[14];
  const float* fco  = (const float*)d_in[15];
  const float* filw = (const float*)d_in[16];
  const float* plo  = (const float*)d_in[17];
  const float* fihw = (const float*)d_in[18];
  const float* phi  = (const float*)d_in[19];
  const float* glw_ih = (const float*)d_in[20];
  const float* glw_hh = (const float*)d_in[21];
  const float* glb_ih = (const float*)d_in[22];
  const float* glb_hh = (const float*)d_in[23];
  const float* ghw_ih = (const float*)d_in[24];
  const float* ghw_hh = (const float*)d_in[25];
  const float* ghb_ih = (const float*)d_in[26];
  const float* ghb_hh = (const float*)d_in[27];
  const float* folw = (const float*)d_in[28];
  const float* fohw = (const float*)d_in[29];

  // big Gi scratch lives in d_out (fully overwritten by k7 at the end)
  float* outf = (float*)d_out;
  float* giL = outf;                      // [T,B,192] 12,582,912
  float* gi0 = outf + 12582912;           // [T,B,96]   6,291,456
  float* giH = outf + 18874368;           // [T,B,96]   6,291,456

  float* ws    = (float*)d_ws;
  float* wc    = ws;                      // 6144
  float* bc    = ws + 6144;               // 96
  float* lowx  = ws + 8192;               // [T,B,64]  4,194,304
  float* highx = ws + 4202496;            // [T,B,32]  2,097,152
  float* bmA   = ws + 6299648;            // [B,T,32]  2,097,152
  float* acc   = ws + 8396800;            // [T,B,64]  4,194,304
  float* dfh   = ws + 12591104;           // [T,B,32]  2,097,152
  float* out   = (float*)d_out;

  k0<<<24, 256, 0, stream>>>(s1w, s1b, wih0, bih0, wc, bc);
  k1<<<24576, 256, 0, stream>>>(mi, wc, bc, gi0);
  k2<<<256, 64, 0, stream>>>(gi0, whh0, bhh0, wih1, whh1, bih1, bhh1, fco, bmA);
  k4<<<8192, 192, 0, stream>>>(lpi, bmA, filw, plo, fihw, phi, lowx, highx);
  k4b<<<49152, 256, 0, stream>>>(lowx, glw_ih, glb_ih, giL);
  k4c<<<24576, 256, 0, stream>>>(highx, ghw_ih, ghb_ih, giH);
  k5<<<256, 128, 0, stream>>>(giL, glw_ih, glw_hh, glb_ih, glb_hh, acc);
  k6<<<256, 64, 0, stream>>>(giH, ghw_hh, ghb_hh, dfh);
  k7<<<2048, 256, 0, stream>>>(acc, dfh, bmA, folw, fohw, spec, out);
}

// Round 3
// 1119.636 us; speedup vs baseline: 1.3952x; 1.3734x over previous
//
#include <hip/hip_runtime.h>
#include <math.h>

#define Bn 256
#define Tn 256

__constant__ int EB[32] = {0,3,5,8,10,13,15,18,22,25,29,33,38,42,48,53,59,66,73,80,89,97,107,117,128,140,153,167,183,199,216,256};

__device__ __forceinline__ float fsig(float x){ return __builtin_amdgcn_rcpf(1.f + __expf(-x)); }
__device__ __forceinline__ float ftanh(float x){ return 1.f - 2.f*__builtin_amdgcn_rcpf(1.f + __expf(2.f*x)); }

__device__ __forceinline__ void gload16(const float* g, float* l){
  __builtin_amdgcn_global_load_lds((const __attribute__((address_space(1))) void*)g,
                                   (__attribute__((address_space(3))) void*)l, 16, 0, 0);
}

#define DOT16(res, X, W) do{ float _s0=0.f,_s1=0.f,_s2=0.f,_s3=0.f; \
  _Pragma("unroll") for (int _e=0;_e<4;++_e){ \
    _s0=fmaf((X)[_e],(W)[_e],_s0); _s1=fmaf((X)[4+_e],(W)[4+_e],_s1); \
    _s2=fmaf((X)[8+_e],(W)[8+_e],_s2); _s3=fmaf((X)[12+_e],(W)[12+_e],_s3);} \
  (res)=(_s0+_s1)+(_s2+_s3); }while(0)

#define DOT8(res, X, W) do{ float _s0=0.f,_s1=0.f; \
  _Pragma("unroll") for (int _e=0;_e<4;++_e){ \
    _s0=fmaf((X)[_e],(W)[_e],_s0); _s1=fmaf((X)[4+_e],(W)[4+_e],_s1);} \
  (res)=_s0+_s1; }while(0)

// ---------- k0: weight prep. wcT[64][96] (fc_in folded into GRU0 wih, transposed),
// bc[96], wLT[2][32][96] (low layer0 wih^T), wHT[2][16][48] (high wih^T)
__global__ __launch_bounds__(256) void k0(const float* __restrict__ wfc, const float* __restrict__ bfc,
    const float* __restrict__ wih0, const float* __restrict__ bih0,
    const float* __restrict__ glw_ih, const float* __restrict__ ghw_ih,
    float* __restrict__ wcT, float* __restrict__ bc,
    float* __restrict__ wLT, float* __restrict__ wHT){
  int i = blockIdx.x*256 + threadIdx.x;
  if (i < 6144){
    int k = i/96, o = i - (i/96)*96;
    float s = 0.f;
    #pragma unroll
    for (int kk = 0; kk < 32; ++kk) s = fmaf(wih0[o*32+kk], wfc[kk*64+k], s);
    wcT[i] = s;
  } else if (i < 6240){
    int o = i - 6144;
    float s = bih0[o];
    #pragma unroll
    for (int kk = 0; kk < 32; ++kk) s = fmaf(wih0[o*32+kk], bfc[kk], s);
    bc[o] = s;
  } else if (i < 12384){
    int j = i - 6240;
    int g = j/3072, k = (j/96) & 31, r = j - (j/96)*96;
    wLT[j] = glw_ih[(g*96+r)*32 + k];
  } else if (i < 13920){
    int j = i - 12384;
    int g = j/768, k = (j/48) & 15, r = j - (j/48)*48;
    wHT[j] = ghw_ih[(g*48+r)*16 + k];
  }
}

// ---------- k1: gi0[b][t][96] = x(b,t) @ wcT + bc (coalesced wT loads, broadcast x)
__global__ __launch_bounds__(256) void k1(const float* __restrict__ mi,
    const float* __restrict__ wcT, const float* __restrict__ bc,
    float* __restrict__ gi0){
  int idx = blockIdx.x*256 + threadIdx.x;
  int o = idx % 96; int bt = idx / 96;
  int b = bt >> 8, t = bt & 255;
  const float4* cur4 = (const float4*)(mi + (b*Tn + t)*32);
  const float4* prv4 = cur4 - 8;
  float s0=0.f,s1=0.f,s2=0.f,s3=0.f;
  #pragma unroll
  for (int j = 0; j < 8; ++j){
    float4 c = cur4[j];
    float4 p = make_float4(0.f,0.f,0.f,0.f);
    if (t > 0) p = prv4[j];
    int f = j*8;
    s0 = fmaf(p.x, wcT[(f+0)*96+o], s0); s0 = fmaf(c.x, wcT[(f+1)*96+o], s0);
    s1 = fmaf(p.y, wcT[(f+2)*96+o], s1); s1 = fmaf(c.y, wcT[(f+3)*96+o], s1);
    s2 = fmaf(p.z, wcT[(f+4)*96+o], s2); s2 = fmaf(c.z, wcT[(f+5)*96+o], s2);
    s3 = fmaf(p.w, wcT[(f+6)*96+o], s3); s3 = fmaf(c.w, wcT[(f+7)*96+o], s3);
  }
  gi0[idx] = bc[o] + ((s0+s1)+(s2+s3));
}

// ---------- k2: stage1 double GRU + band-mask fc. 1 wave/batch, LDS gi chunks.
__global__ __launch_bounds__(64,1) void k2(const float* __restrict__ gi0,
    const float* __restrict__ whh0, const float* __restrict__ bhh0,
    const float* __restrict__ wih1, const float* __restrict__ whh1,
    const float* __restrict__ bih1, const float* __restrict__ bhh1,
    const float* __restrict__ fco, float* __restrict__ bmA)
{
  const int lane = threadIdx.x;
  const int q = lane >> 5, h = lane & 31, ko = q*16;
  const int b = blockIdx.x;
  float a0h[3][16], a1i[3][16], a1h[3][16], afc[16];
  #pragma unroll
  for (int g = 0; g < 3; ++g){
    const float* w0 = whh0 + (g*32+h)*32 + ko;
    const float* wi = wih1 + (g*32+h)*32 + ko;
    const float* wh = whh1 + (g*32+h)*32 + ko;
    #pragma unroll
    for (int k = 0; k < 16; ++k){ a0h[g][k]=w0[k]; a1i[g][k]=wi[k]; a1h[g][k]=wh[k]; }
  }
  #pragma unroll
  for (int k = 0; k < 16; ++k) afc[k] = fco[(ko+k)*32 + h];
  const float bh0r = bhh0[h], bh0z = bhh0[32+h], bh0n = bhh0[64+h];
  const float b1r = bih1[h]+bhh1[h], b1z = bih1[32+h]+bhh1[32+h];
  const float bi1n = bih1[64+h], bh1n = bhh1[64+h];

  __shared__ __attribute__((aligned(16))) float gib[2][6144];
  __shared__ __attribute__((aligned(16))) float h1arr[32];
  __shared__ __attribute__((aligned(16))) float h2arr[32];
  const float* gsrc = gi0 + b*24576;
  #pragma unroll
  for (int c0 = 0; c0 < 2; ++c0)
    for (int it = 0; it < 24; ++it)
      gload16(gsrc + c0*6144 + it*256 + lane*4, &gib[c0][it*256]);
  asm volatile("s_waitcnt vmcnt(24)" ::: "memory");

  float h1v[16], h2v[16];
  #pragma unroll
  for (int k = 0; k < 16; ++k){ h1v[k]=0.f; h2v[k]=0.f; }
  float h1own = 0.f, h2own = 0.f;

  for (int t = 0; t < Tn; ++t){
    if ((t & 63) == 0 && t){
      int c = t >> 6;
      if (c < 3){
        const float* gs = gsrc + (c+1)*6144;
        for (int it = 0; it < 24; ++it)
          gload16(gs + it*256 + lane*4, &gib[(c+1)&1][it*256]);
        asm volatile("s_waitcnt vmcnt(24)" ::: "memory");
      } else {
        asm volatile("s_waitcnt vmcnt(0)" ::: "memory");
      }
    }
    const float* gt = &gib[(t>>6)&1][(t&63)*96];
    float c_r = gt[h], c_z = gt[32+h], c_n = gt[64+h];
    float pr, pz, pn;
    DOT16(pr, h1v, a0h[0]); DOT16(pz, h1v, a0h[1]); DOT16(pn, h1v, a0h[2]);
    pr += __shfl_xor(pr,32); pz += __shfl_xor(pz,32); pn += __shfl_xor(pn,32);
    float r = fsig(c_r + pr + bh0r);
    float z = fsig(c_z + pz + bh0z);
    float nn = ftanh(c_n + r*(pn + bh0n));
    float hn1 = nn + z*(h1own - nn);
    h1own = hn1;
    h1arr[h] = hn1;
    *(float4*)&h1v[0]  = *(const float4*)&h1arr[ko+0];
    *(float4*)&h1v[4]  = *(const float4*)&h1arr[ko+4];
    *(float4*)&h1v[8]  = *(const float4*)&h1arr[ko+8];
    *(float4*)&h1v[12] = *(const float4*)&h1arr[ko+12];
    float ur, uz, ui, vr, vz, vh;
    DOT16(ur, h1v, a1i[0]); DOT16(uz, h1v, a1i[1]); DOT16(ui, h1v, a1i[2]);
    DOT16(vr, h2v, a1h[0]); DOT16(vz, h2v, a1h[1]); DOT16(vh, h2v, a1h[2]);
    float qr = ur+vr, qz = uz+vz;
    qr += __shfl_xor(qr,32); qz += __shfl_xor(qz,32);
    ui += __shfl_xor(ui,32); vh += __shfl_xor(vh,32);
    float r1 = fsig(qr + b1r);
    float z1 = fsig(qz + b1z);
    float n1 = ftanh(ui + bi1n + r1*(vh + bh1n));
    float hn2 = n1 + z1*(h2own - n1);
    h2own = hn2;
    h2arr[h] = hn2;
    *(float4*)&h2v[0]  = *(const float4*)&h2arr[ko+0];
    *(float4*)&h2v[4]  = *(const float4*)&h2arr[ko+4];
    *(float4*)&h2v[8]  = *(const float4*)&h2arr[ko+8];
    *(float4*)&h2v[12] = *(const float4*)&h2arr[ko+12];
    float x1v[16];
    #pragma unroll
    for (int k = 0; k < 16; ++k) x1v[k] = h1v[k] + h2v[k];
    float s;
    DOT16(s, x1v, afc);
    s += __shfl_xor(s,32);
    if (q == 0) bmA[(b*Tn + t)*32 + h] = fsig(s);
  }
}

// ---------- k4: low/high fc_in + PReLU (unchanged, passing)
__global__ __launch_bounds__(192) void k4(const float* __restrict__ lpi,
    const float* __restrict__ bmA,
    const float* __restrict__ wlo, const float* __restrict__ plo,
    const float* __restrict__ whi, const float* __restrict__ phi,
    float* __restrict__ lowx, float* __restrict__ highx)
{
  int tid = threadIdx.x;
  int pair = tid / 24;
  int c = tid - pair*24;
  int bt = blockIdx.x*8 + pair;
  int b = bt >> 8, t = bt & 255;
  const float* lrow = lpi + (b*Tn + t)*256;
  const float* brow = bmA + (b*Tn + t)*32;
  if (c < 16){
    float4 p = {0.f,0.f,0.f,0.f};
    for (int i = 0; i < 128; ++i){
      float v = lrow[i];
      float4 wv = *(const float4*)&wlo[i*64 + c*4];
      p.x = fmaf(v, wv.x, p.x); p.y = fmaf(v, wv.y, p.y);
      p.z = fmaf(v, wv.z, p.z); p.w = fmaf(v, wv.w, p.w);
    }
    for (int i = 0; i < 32; ++i){
      float v = brow[i];
      float4 wv = *(const float4*)&wlo[(128+i)*64 + c*4];
      p.x = fmaf(v, wv.x, p.x); p.y = fmaf(v, wv.y, p.y);
      p.z = fmaf(v, wv.z, p.z); p.w = fmaf(v, wv.w, p.w);
    }
    float a = plo[0];
    p.x = p.x >= 0.f ? p.x : a*p.x;
    p.y = p.y >= 0.f ? p.y : a*p.y;
    p.z = p.z >= 0.f ? p.z : a*p.z;
    p.w = p.w >= 0.f ? p.w : a*p.w;
    *(float4*)&lowx[(t*Bn + b)*64 + c*4] = p;
  } else {
    int c2 = c - 16;
    int g = c2 >> 2;
    int oo = (c2 & 3)*4;
    float4 p = {0.f,0.f,0.f,0.f};
    for (int i = 0; i < 80; ++i){
      int idx = g*80 + i;
      float v = (idx < 128) ? lrow[128 + idx] : brow[idx - 128];
      float4 wv = *(const float4*)&whi[(g*80 + i)*16 + oo];
      p.x = fmaf(v, wv.x, p.x); p.y = fmaf(v, wv.y, p.y);
      p.z = fmaf(v, wv.z, p.z); p.w = fmaf(v, wv.w, p.w);
    }
    float a = phi[0];
    p.x = p.x >= 0.f ? p.x : a*p.x;
    p.y = p.y >= 0.f ? p.y : a*p.y;
    p.z = p.z >= 0.f ? p.z : a*p.z;
    p.w = p.w >= 0.f ? p.w : a*p.w;
    *(float4*)&highx[(t*Bn + b)*32 + g*16 + oo] = p;
  }
}

// ---------- k4b: giL[b][t][192] = lowx_g @ wLT + bih (coalesced wT loads)
__global__ __launch_bounds__(256) void k4b(const float* __restrict__ lowx,
    const float* __restrict__ wLT, const float* __restrict__ bih,
    float* __restrict__ giL){
  int idx = blockIdx.x*256 + threadIdx.x;
  int o = idx % 192; int bt = idx / 192;
  int b = bt >> 8, t = bt & 255;
  int g = o / 96, r = o - g*96;
  const float4* x4 = (const float4*)(lowx + (t*Bn + b)*64 + g*32);
  const float* w = wLT + g*3072 + r;
  float s0=0.f,s1=0.f,s2=0.f,s3=0.f;
  #pragma unroll
  for (int j = 0; j < 8; ++j){
    float4 a = x4[j];
    s0 = fmaf(a.x, w[(j*4+0)*96], s0);
    s1 = fmaf(a.y, w[(j*4+1)*96], s1);
    s2 = fmaf(a.z, w[(j*4+2)*96], s2);
    s3 = fmaf(a.w, w[(j*4+3)*96], s3);
  }
  giL[idx] = bih[g*96 + r] + ((s0+s1)+(s2+s3));
}

// ---------- k4c: giH[b][t][96] = highx_g @ wHT + bih
__global__ __launch_bounds__(256) void k4c(const float* __restrict__ highx,
    const float* __restrict__ wHT, const float* __restrict__ bih,
    float* __restrict__ giH){
  int idx = blockIdx.x*256 + threadIdx.x;
  int o = idx % 96; int bt = idx / 96;
  int b = bt >> 8, t = bt & 255;
  int g = o / 48, r = o - g*48;
  const float4* x4 = (const float4*)(highx + (t*Bn + b)*32 + g*16);
  const float* w = wHT + g*768 + r;
  float s0=0.f,s1=0.f,s2=0.f,s3=0.f;
  #pragma unroll
  for (int j = 0; j < 4; ++j){
    float4 a = x4[j];
    s0 = fmaf(a.x, w[(j*4+0)*48], s0);
    s1 = fmaf(a.y, w[(j*4+1)*48], s1);
    s2 = fmaf(a.z, w[(j*4+2)*48], s2);
    s3 = fmaf(a.w, w[(j*4+3)*48], s3);
  }
  giH[idx] = bih[g*48 + r] + ((s0+s1)+(s2+s3));
}

// ---------- k5: low grouped 2-layer GRU + shuffle. 2 waves (wave = group), raw barrier.
__global__ __launch_bounds__(128,1) void k5(const float* __restrict__ giL,
    const float* __restrict__ wih, const float* __restrict__ whh,
    const float* __restrict__ bih, const float* __restrict__ bhh,
    float* __restrict__ acc)
{
  const int tid = threadIdx.x;
  const int g = tid >> 6;
  const int lane = tid & 63;
  const int q = lane >> 5, h = lane & 31, ko = q*16;
  const int b = blockIdx.x;
  float a0h[3][16], a1i[3][16], a1h[3][16];
  #pragma unroll
  for (int gt_ = 0; gt_ < 3; ++gt_){
    const float* w0 = whh + (g*96 + gt_*32 + h)*32 + ko;
    const float* wi = wih + ((2+g)*96 + gt_*32 + h)*32 + ko;
    const float* wh = whh + ((2+g)*96 + gt_*32 + h)*32 + ko;
    #pragma unroll
    for (int k = 0; k < 16; ++k){
      int pk = (k < 8) ? 2*k : 2*(k-8)+1;   // permuted to match even/odd ybuf reads
      a0h[gt_][k] = w0[pk];
      a1i[gt_][k] = wi[k];
      a1h[gt_][k] = wh[k];
    }
  }
  const float bh0r = bhh[g*96+h], bh0z = bhh[g*96+32+h], bh0n = bhh[g*96+64+h];
  const float b1r = bih[(2+g)*96+h] + bhh[(2+g)*96+h];
  const float b1z = bih[(2+g)*96+32+h] + bhh[(2+g)*96+32+h];
  const float bi1n = bih[(2+g)*96+64+h], bh1n = bhh[(2+g)*96+64+h];

  __shared__ __attribute__((aligned(16))) float gib[2][2][3072];
  __shared__ __attribute__((aligned(16))) float ybuf[2][64];
  __shared__ __attribute__((aligned(16))) float h1l[2][32];
  const float* gsrc = giL + b*49152 + g*96;
  #pragma unroll
  for (int c0 = 0; c0 < 2; ++c0)
    for (int it = 0; it < 12; ++it){
      int i = it*64 + lane;
      int toff = i/24, c4 = i - toff*24;
      gload16(gsrc + (c0*32 + toff)*192 + c4*4, &gib[g][c0][it*256]);
    }
  asm volatile("s_waitcnt vmcnt(12)" ::: "memory");

  float h0v[16], h1v[16];
  #pragma unroll
  for (int k = 0; k < 16; ++k){ h0v[k]=0.f; h1v[k]=0.f; }
  float h0own = 0.f, h1own = 0.f;

  for (int t = 0; t < Tn; ++t){
    if ((t & 31) == 0 && t){
      int c = t >> 5;
      if (c < 7){
        for (int it = 0; it < 12; ++it){
          int i = it*64 + lane;
          int toff = i/24, c4 = i - toff*24;
          gload16(gsrc + ((c+1)*32 + toff)*192 + c4*4, &gib[g][(c+1)&1][it*256]);
        }
        asm volatile("s_waitcnt vmcnt(12)" ::: "memory");
      } else {
        asm volatile("s_waitcnt vmcnt(0)" ::: "memory");
      }
    }
    const float* gt = &gib[g][(t>>5)&1][(t&31)*96];
    float c_r = gt[h], c_z = gt[32+h], c_n = gt[64+h];
    float pr, pz, pn;
    DOT16(pr, h0v, a0h[0]); DOT16(pz, h0v, a0h[1]); DOT16(pn, h0v, a0h[2]);
    pr += __shfl_xor(pr,32); pz += __shfl_xor(pz,32); pn += __shfl_xor(pn,32);
    float r = fsig(c_r + pr + bh0r);
    float z = fsig(c_z + pz + bh0z);
    float nn = ftanh(c_n + r*(pn + bh0n));
    float hn0 = nn + z*(h0own - nn);
    h0own = hn0;
    ybuf[t&1][((h&1)<<5) + (g<<4) + (h>>1)] = hn0;   // pre-shuffled position
    asm volatile("s_waitcnt lgkmcnt(0)" ::: "memory");
    __builtin_amdgcn_sched_barrier(0);
    __builtin_amdgcn_s_barrier();
    __builtin_amdgcn_sched_barrier(0);
    const float* yb = ybuf[t&1];
    *(float4*)&h0v[0]  = *(const float4*)&yb[g*16 + (ko>>1)];
    *(float4*)&h0v[4]  = *(const float4*)&yb[g*16 + (ko>>1) + 4];
    *(float4*)&h0v[8]  = *(const float4*)&yb[32 + g*16 + (ko>>1)];
    *(float4*)&h0v[12] = *(const float4*)&yb[32 + g*16 + (ko>>1) + 4];
    float xv[16];
    *(float4*)&xv[0]  = *(const float4*)&yb[g*32 + ko + 0];
    *(float4*)&xv[4]  = *(const float4*)&yb[g*32 + ko + 4];
    *(float4*)&xv[8]  = *(const float4*)&yb[g*32 + ko + 8];
    *(float4*)&xv[12] = *(const float4*)&yb[g*32 + ko + 12];
    float yown = yb[g*32 + h];
    float ur, uz, ui, vr, vz, vh;
    DOT16(ur, xv, a1i[0]); DOT16(uz, xv, a1i[1]); DOT16(ui, xv, a1i[2]);
    DOT16(vr, h1v, a1h[0]); DOT16(vz, h1v, a1h[1]); DOT16(vh, h1v, a1h[2]);
    float qr = ur+vr, qz = uz+vz;
    qr += __shfl_xor(qr,32); qz += __shfl_xor(qz,32);
    ui += __shfl_xor(ui,32); vh += __shfl_xor(vh,32);
    float r1 = fsig(qr + b1r);
    float z1 = fsig(qz + b1z);
    float n1 = ftanh(ui + bi1n + r1*(vh + bh1n));
    float hn1 = n1 + z1*(h1own - n1);
    h1own = hn1;
    h1l[g][h] = hn1;
    *(float4*)&h1v[0]  = *(const float4*)&h1l[g][ko+0];
    *(float4*)&h1v[4]  = *(const float4*)&h1l[g][ko+4];
    *(float4*)&h1v[8]  = *(const float4*)&h1l[g][ko+8];
    *(float4*)&h1v[12] = *(const float4*)&h1l[g][ko+12];
    if (q == 0) acc[(t*Bn + b)*64 + g*32 + h] = yown + hn1;
  }
}

// ---------- k6: high grouped GRU (2 groups, H=16). 1 wave/batch, LDS gi chunks.
__global__ __launch_bounds__(64,1) void k6(const float* __restrict__ giH,
    const float* __restrict__ whh, const float* __restrict__ bhh,
    float* __restrict__ dfh)
{
  const int lane = threadIdx.x;
  const int g = lane >> 5, q = (lane >> 4) & 1, h = lane & 15, ko = q*8;
  const int b = blockIdx.x;
  float ah[3][8];
  #pragma unroll
  for (int gt_ = 0; gt_ < 3; ++gt_){
    const float* w = whh + (g*48 + gt_*16 + h)*16 + ko;
    #pragma unroll
    for (int k = 0; k < 8; ++k) ah[gt_][k] = w[k];
  }
  const float bhr = bhh[g*48+h], bhz = bhh[g*48+16+h], bhn = bhh[g*48+32+h];
  __shared__ __attribute__((aligned(16))) float gib[2][6144];
  __shared__ __attribute__((aligned(16))) float harr[32];
  const float* gsrc = giH + b*24576;
  #pragma unroll
  for (int c0 = 0; c0 < 2; ++c0)
    for (int it = 0; it < 24; ++it)
      gload16(gsrc + c0*6144 + it*256 + lane*4, &gib[c0][it*256]);
  asm volatile("s_waitcnt vmcnt(24)" ::: "memory");

  float hv[8];
  #pragma unroll
  for (int k = 0; k < 8; ++k) hv[k] = 0.f;
  float hown = 0.f;

  for (int t = 0; t < Tn; ++t){
    if ((t & 63) == 0 && t){
      int c = t >> 6;
      if (c < 3){
        const float* gs = gsrc + (c+1)*6144;
        for (int it = 0; it < 24; ++it)
          gload16(gs + it*256 + lane*4, &gib[(c+1)&1][it*256]);
        asm volatile("s_waitcnt vmcnt(24)" ::: "memory");
      } else {
        asm volatile("s_waitcnt vmcnt(0)" ::: "memory");
      }
    }
    const float* gt = &gib[(t>>6)&1][(t&63)*96 + g*48];
    float c_r = gt[h], c_z = gt[16+h], c_n = gt[32+h];
    float pr, pz, pn;
    DOT8(pr, hv, ah[0]); DOT8(pz, hv, ah[1]); DOT8(pn, hv, ah[2]);
    pr += __shfl_xor(pr,16); pz += __shfl_xor(pz,16); pn += __shfl_xor(pn,16);
    float r = fsig(c_r + pr + bhr);
    float z = fsig(c_z + pz + bhz);
    float nn = ftanh(c_n + r*(pn + bhn));
    float hn = nn + z*(hown - nn);
    hown = hn;
    harr[g*16 + h] = hn;
    *(float4*)&hv[0] = *(const float4*)&harr[g*16 + ko + 0];
    *(float4*)&hv[4] = *(const float4*)&harr[g*16 + ko + 4];
    if (q == 0) dfh[(t*Bn + b)*32 + g*16 + h] = hn;
  }
}

// ---------- k7: full_mask from bmA + mask_low/high fc + final fusion (unchanged)
__global__ __launch_bounds__(256) void k7(const float* __restrict__ acc,
    const float* __restrict__ dfh, const float* __restrict__ bmA,
    const float* __restrict__ wlo, const float* __restrict__ whi,
    const float* __restrict__ spec, float* __restrict__ out)
{
  __shared__ float accs[32][65];
  __shared__ float dfhs[32][33];
  __shared__ float bmt[32][33];
  __shared__ float mlds[128][32];
  __shared__ float mhds[128][32];
  __shared__ float frcs[257];
  __shared__ int   ibds[257];
  const int tid = threadIdx.x;
  const int b  = blockIdx.x >> 3;
  const int t0 = (blockIdx.x & 7) * 32;
  for (int idx = tid; idx < 32*16; idx += 256){
    int tl = idx >> 4, c4 = (idx & 15)*4;
    float4 v = *(const float4*)&acc[((t0 + tl)*Bn + b)*64 + c4];
    accs[tl][c4] = v.x; accs[tl][c4+1] = v.y; accs[tl][c4+2] = v.z; accs[tl][c4+3] = v.w;
  }
  for (int idx = tid; idx < 32*8; idx += 256){
    int tl = idx >> 3, c4 = (idx & 7)*4;
    float4 v = *(const float4*)&dfh[((t0 + tl)*Bn + b)*32 + c4];
    dfhs[tl][c4] = v.x; dfhs[tl][c4+1] = v.y; dfhs[tl][c4+2] = v.z; dfhs[tl][c4+3] = v.w;
    float4 u = *(const float4*)&bmA[(b*Tn + t0 + tl)*32 + c4];
    bmt[tl][c4] = u.x; bmt[tl][c4+1] = u.y; bmt[tl][c4+2] = u.z; bmt[tl][c4+3] = u.w;
  }
  for (int f = tid; f < 257; f += 256){
    int i = 0;
    #pragma unroll
    for (int k = 1; k < 31; ++k) if (f >= EB[k]) i = k;
    ibds[f] = i;
    frcs[f] = (f < 256) ? (float)(f - EB[i]) / (float)(EB[i+1] - EB[i]) : 0.f;
  }
  __syncthreads();
  const int tl = tid & 31, fo = tid >> 5;
  {
    float p[16];
    #pragma unroll
    for (int j = 0; j < 16; ++j) p[j] = 0.f;
    for (int i = 0; i < 64; ++i){
      float a = accs[tl][i];
      const float4* wr = (const float4*)&wlo[i*128 + fo*16];
      #pragma unroll
      for (int j4 = 0; j4 < 4; ++j4){
        float4 wv = wr[j4];
        p[j4*4+0] = fmaf(a, wv.x, p[j4*4+0]);
        p[j4*4+1] = fmaf(a, wv.y, p[j4*4+1]);
        p[j4*4+2] = fmaf(a, wv.z, p[j4*4+2]);
        p[j4*4+3] = fmaf(a, wv.w, p[j4*4+3]);
      }
    }
    #pragma unroll
    for (int j = 0; j < 16; ++j) mlds[fo*16 + j][tl] = fsig(p[j]);
  }
  {
    float p[16];
    #pragma unroll
    for (int j = 0; j < 16; ++j) p[j] = 0.f;
    const int g = fo >> 2, ob = (fo & 3)*16;
    for (int i = 0; i < 16; ++i){
      float a = dfhs[tl][g*16 + i];
      const float4* wr = (const float4*)&whi[(g*16 + i)*64 + ob];
      #pragma unroll
      for (int j4 = 0; j4 < 4; ++j4){
        float4 wv = wr[j4];
        p[j4*4+0] = fmaf(a, wv.x, p[j4*4+0]);
        p[j4*4+1] = fmaf(a, wv.y, p[j4*4+1]);
        p[j4*4+2] = fmaf(a, wv.z, p[j4*4+2]);
        p[j4*4+3] = fmaf(a, wv.w, p[j4*4+3]);
      }
    }
    #pragma unroll
    for (int j = 0; j < 16; ++j) mhds[fo*16 + j][tl] = fsig(p[j]);
  }
  __syncthreads();
  float* out1 = out + 16842752;
  float* out2 = out + 2*16842752;
  float2* out3 = (float2*)(out + 3*16842752);
  const float2* sp2 = (const float2*)spec;
  for (int f = fo; f < 257; f += 8){
    int base = (b*257 + f)*Tn + t0 + tl;
    float full;
    if (f < 256){
      int i = ibds[f]; float fr = frcs[f];
      full = bmt[tl][i]*(1.f - fr) + bmt[tl][i+1]*fr;
    } else full = 0.f;
    float m = (f < 128) ? mlds[f][tl]*full
            : (f < 256 ? mhds[f-128][tl]*full : full);
    float2 s = sp2[base];
    float ox = s.x*full, oy = s.y*full;
    float sx = ox*m, sy = oy*m;
    out[base]  = full;
    out1[base] = m;
    out2[base] = sqrtf(sx*sx + sy*sy);
    out3[base] = make_float2(sx, sy);
  }
}

extern "C" void kernel_launch(void* const* d_in, const int* in_sizes, int n_in,
                              void* d_out, int out_size, void* d_ws, size_t ws_size,
                              hipStream_t stream){
  const float* mi   = (const float*)d_in[0];
  const float* spec = (const float*)d_in[1];
  const float* lpi  = (const float*)d_in[2];
  const float* s1w  = (const float*)d_in[5];
  const float* s1b  = (const float*)d_in[6];
  const float* wih0 = (const float*)d_in[7];
  const float* whh0 = (const float*)d_in[8];
  const float* bih0 = (const float*)d_in[9];
  const float* bhh0 = (const float*)d_in[10];
  const float* wih1 = (const float*)d_in[11];
  const float* whh1 = (const float*)d_in[12];
  const float* bih1 = (const float*)d_in[13];
  const float* bhh1 = (const float*)d_in[14];
  const float* fco  = (const float*)d_in[15];
  const float* filw = (const float*)d_in[16];
  const float* plo  = (const float*)d_in[17];
  const float* fihw = (const float*)d_in[18];
  const float* phi  = (const float*)d_in[19];
  const float* glw_ih = (const float*)d_in[20];
  const float* glw_hh = (const float*)d_in[21];
  const float* glb_ih = (const float*)d_in[22];
  const float* glb_hh = (const float*)d_in[23];
  const float* ghw_ih = (const float*)d_in[24];
  const float* ghw_hh = (const float*)d_in[25];
  const float* ghb_ih = (const float*)d_in[26];
  const float* ghb_hh = (const float*)d_in[27];
  const float* folw = (const float*)d_in[28];
  const float* fohw = (const float*)d_in[29];

  // big Gi scratch lives in d_out (fully overwritten by k7 at the end)
  float* outf = (float*)d_out;
  float* giL = outf;                      // [B][T][192] 12,582,912
  float* gi0 = outf + 12582912;           // [B][T][96]   6,291,456
  float* giH = outf + 18874368;           // [B][T][96]   6,291,456

  float* ws    = (float*)d_ws;
  float* wcT   = ws;                      // 6144
  float* bc    = ws + 6144;               // 96
  float* wLT   = ws + 6240;               // 6144
  float* wHT   = ws + 12384;              // 1536
  float* lowx  = ws + 14336;              // [T,B,64]  4,194,304
  float* highx = ws + 4208640;            // [T,B,32]  2,097,152
  float* bmA   = ws + 6305792;            // [B,T,32]  2,097,152
  float* acc   = ws + 8402944;            // [T,B,64]  4,194,304
  float* dfh   = ws + 12597248;           // [T,B,32]  2,097,152
  float* out   = (float*)d_out;

  k0<<<55, 256, 0, stream>>>(s1w, s1b, wih0, bih0, glw_ih, ghw_ih, wcT, bc, wLT, wHT);
  k1<<<24576, 256, 0, stream>>>(mi, wcT, bc, gi0);
  k2<<<256, 64, 0, stream>>>(gi0, whh0, bhh0, wih1, whh1, bih1, bhh1, fco, bmA);
  k4<<<8192, 192, 0, stream>>>(lpi, bmA, filw, plo, fihw, phi, lowx, highx);
  k4b<<<49152, 256, 0, stream>>>(lowx, wLT, glb_ih, giL);
  k4c<<<24576, 256, 0, stream>>>(highx, wHT, ghb_ih, giH);
  k5<<<256, 128, 0, stream>>>(giL, glw_ih, glw_hh, glb_ih, glb_hh, acc);
  k6<<<256, 64, 0, stream>>>(giH, ghw_hh, ghb_hh, dfh);
  k7<<<2048, 256, 0, stream>>>(acc, dfh, bmA, folw, fohw, spec, out);
}

// Round 4
// 784.797 us; speedup vs baseline: 1.9905x; 1.4267x over previous
//
#include <hip/hip_runtime.h>
#include <math.h>

#define Bn 256
#define Tn 256

__constant__ int EB[32] = {0,3,5,8,10,13,15,18,22,25,29,33,38,42,48,53,59,66,73,80,89,97,107,117,128,140,153,167,183,199,216,256};

__device__ __forceinline__ float fsig(float x){ return __builtin_amdgcn_rcpf(1.f + __expf(-x)); }
__device__ __forceinline__ float ftanh(float x){ return 1.f - 2.f*__builtin_amdgcn_rcpf(1.f + __expf(2.f*x)); }

__device__ __forceinline__ void gload16(const float* g, float* l){
  __builtin_amdgcn_global_load_lds((const __attribute__((address_space(1))) void*)g,
                                   (__attribute__((address_space(3))) void*)l, 16, 0, 0);
}

#define DOT16(res, X, W) do{ float _s0=0.f,_s1=0.f,_s2=0.f,_s3=0.f; \
  _Pragma("unroll") for (int _e=0;_e<4;++_e){ \
    _s0=fmaf((X)[_e],(W)[_e],_s0); _s1=fmaf((X)[4+_e],(W)[4+_e],_s1); \
    _s2=fmaf((X)[8+_e],(W)[8+_e],_s2); _s3=fmaf((X)[12+_e],(W)[12+_e],_s3);} \
  (res)=(_s0+_s1)+(_s2+_s3); }while(0)

#define DOT8(res, X, W) do{ float _s0=0.f,_s1=0.f; \
  _Pragma("unroll") for (int _e=0;_e<4;++_e){ \
    _s0=fmaf((X)[_e],(W)[_e],_s0); _s1=fmaf((X)[4+_e],(W)[4+_e],_s1);} \
  (res)=_s0+_s1; }while(0)

// acc[4 outs] += x(float4 over k) * w[4 k](float4 over outs)
#define FMA44(A, X, W) do{ \
  (A)[0]=fmaf((X).x,(W)[0].x,(A)[0]); (A)[1]=fmaf((X).x,(W)[0].y,(A)[1]); (A)[2]=fmaf((X).x,(W)[0].z,(A)[2]); (A)[3]=fmaf((X).x,(W)[0].w,(A)[3]); \
  (A)[0]=fmaf((X).y,(W)[1].x,(A)[0]); (A)[1]=fmaf((X).y,(W)[1].y,(A)[1]); (A)[2]=fmaf((X).y,(W)[1].z,(A)[2]); (A)[3]=fmaf((X).y,(W)[1].w,(A)[3]); \
  (A)[0]=fmaf((X).z,(W)[2].x,(A)[0]); (A)[1]=fmaf((X).z,(W)[2].y,(A)[1]); (A)[2]=fmaf((X).z,(W)[2].z,(A)[2]); (A)[3]=fmaf((X).z,(W)[2].w,(A)[3]); \
  (A)[0]=fmaf((X).w,(W)[3].x,(A)[0]); (A)[1]=fmaf((X).w,(W)[3].y,(A)[1]); (A)[2]=fmaf((X).w,(W)[3].z,(A)[2]); (A)[3]=fmaf((X).w,(W)[3].w,(A)[3]); \
}while(0)

// ---------- k0: weight prep.
// wcT[64][96] = (fc_in folded into GRU0 wih)^T, bc[96],
// wBT: stepB weights: [48 og][32 k][4 outs] (giL layer0) + [24 og][16 k][4 outs] (giH), bB[288]
__global__ __launch_bounds__(256) void k0(const float* __restrict__ wfc, const float* __restrict__ bfc,
    const float* __restrict__ wih0, const float* __restrict__ bih0,
    const float* __restrict__ glw_ih, const float* __restrict__ glb_ih,
    const float* __restrict__ ghw_ih, const float* __restrict__ ghb_ih,
    float* __restrict__ wcT, float* __restrict__ bc,
    float* __restrict__ wBT, float* __restrict__ bB){
  int i = blockIdx.x*256 + threadIdx.x;
  if (i < 6144){
    int k = i/96, o = i - (i/96)*96;
    float s = 0.f;
    #pragma unroll
    for (int kk = 0; kk < 32; ++kk) s = fmaf(wih0[o*32+kk], wfc[kk*64+k], s);
    wcT[i] = s;
  } else if (i < 6240){
    int o = i - 6144;
    float s = bih0[o];
    #pragma unroll
    for (int kk = 0; kk < 32; ++kk) s = fmaf(wih0[o*32+kk], bfc[kk], s);
    bc[o] = s;
  } else if (i < 13920){
    int j = i - 6240;
    if (j < 6144){
      int og = j >> 7, rem = j & 127, k = rem >> 2, jj = rem & 3;
      int o = og*4 + jj; int g = o/96, r = o - g*96;
      wBT[j] = glw_ih[(g*96 + r)*32 + k];
    } else {
      int j2 = j - 6144;
      int oh = j2 >> 6, rem = j2 & 63, k = rem >> 2, jj = rem & 3;
      int o = oh*4 + jj; int g = o/48, r = o - g*48;
      wBT[j] = ghw_ih[(g*48 + r)*16 + k];
    }
  } else if (i < 14208){
    int o = i - 13920;
    bB[o] = (o < 192) ? glb_ih[o] : ghb_ih[o - 192];
  }
}

// ---------- k1: gi0[b][t][96] = x(b,t) @ wcT + bc. Register-tiled: 4 outs x 4 t per thread.
__global__ __launch_bounds__(256) void k1(const float* __restrict__ mi,
    const float* __restrict__ wcT, const float* __restrict__ bc,
    float* __restrict__ gi0){
  __shared__ float mbuf[33*36];   // rows t0-1 .. t0+31, stride 36
  const int tid = threadIdx.x;
  const int b = blockIdx.x >> 3;
  const int t0 = (blockIdx.x & 7)*32;
  const int bt0 = b*256 + t0;
  for (int idx = tid; idx < 264; idx += 256){
    int row = idx >> 3, c4 = idx & 7;
    int r = t0 - 1 + row;
    float4 v = make_float4(0.f,0.f,0.f,0.f);
    if (r >= 0) v = *(const float4*)&mi[(b*256 + r)*32 + c4*4];
    *(float4*)&mbuf[row*36 + c4*4] = v;
  }
  __syncthreads();
  const int og = tid >> 3, btg = tid & 7;
  if (og >= 24) return;
  float acc[4][4];
  #pragma unroll
  for (int bj = 0; bj < 4; ++bj){ acc[bj][0]=0.f; acc[bj][1]=0.f; acc[bj][2]=0.f; acc[bj][3]=0.f; }
  for (int fq = 0; fq < 8; ++fq){
    float4 wvp[4], wvc[4];
    #pragma unroll
    for (int i = 0; i < 4; ++i){
      int f = fq*4 + i;
      wvp[i] = *(const float4*)&wcT[(2*f)*96 + og*4];
      wvc[i] = *(const float4*)&wcT[(2*f+1)*96 + og*4];
    }
    #pragma unroll
    for (int bj = 0; bj < 4; ++bj){
      int btl = btg + 8*bj;
      float4 xp = *(const float4*)&mbuf[btl*36 + fq*4];
      float4 xc = *(const float4*)&mbuf[(btl+1)*36 + fq*4];
      FMA44(acc[bj], xp, wvp);
      FMA44(acc[bj], xc, wvc);
    }
  }
  float4 bias = *(const float4*)&bc[og*4];
  #pragma unroll
  for (int bj = 0; bj < 4; ++bj){
    int btl = btg + 8*bj;
    float4 o;
    o.x = acc[bj][0] + bias.x; o.y = acc[bj][1] + bias.y;
    o.z = acc[bj][2] + bias.z; o.w = acc[bj][3] + bias.w;
    *(float4*)&gi0[(bt0 + btl)*96 + og*4] = o;
  }
}

// ---------- k2: stage1 double GRU + band-mask fc. 1 wave/batch, LDS gi chunks. (unchanged)
__global__ __launch_bounds__(64,1) void k2(const float* __restrict__ gi0,
    const float* __restrict__ whh0, const float* __restrict__ bhh0,
    const float* __restrict__ wih1, const float* __restrict__ whh1,
    const float* __restrict__ bih1, const float* __restrict__ bhh1,
    const float* __restrict__ fco, float* __restrict__ bmA)
{
  const int lane = threadIdx.x;
  const int q = lane >> 5, h = lane & 31, ko = q*16;
  const int b = blockIdx.x;
  float a0h[3][16], a1i[3][16], a1h[3][16], afc[16];
  #pragma unroll
  for (int g = 0; g < 3; ++g){
    const float* w0 = whh0 + (g*32+h)*32 + ko;
    const float* wi = wih1 + (g*32+h)*32 + ko;
    const float* wh = whh1 + (g*32+h)*32 + ko;
    #pragma unroll
    for (int k = 0; k < 16; ++k){ a0h[g][k]=w0[k]; a1i[g][k]=wi[k]; a1h[g][k]=wh[k]; }
  }
  #pragma unroll
  for (int k = 0; k < 16; ++k) afc[k] = fco[(ko+k)*32 + h];
  const float bh0r = bhh0[h], bh0z = bhh0[32+h], bh0n = bhh0[64+h];
  const float b1r = bih1[h]+bhh1[h], b1z = bih1[32+h]+bhh1[32+h];
  const float bi1n = bih1[64+h], bh1n = bhh1[64+h];

  __shared__ __attribute__((aligned(16))) float gib[2][6144];
  __shared__ __attribute__((aligned(16))) float h1arr[32];
  __shared__ __attribute__((aligned(16))) float h2arr[32];
  const float* gsrc = gi0 + b*24576;
  #pragma unroll
  for (int c0 = 0; c0 < 2; ++c0)
    for (int it = 0; it < 24; ++it)
      gload16(gsrc + c0*6144 + it*256 + lane*4, &gib[c0][it*256]);
  asm volatile("s_waitcnt vmcnt(24)" ::: "memory");

  float h1v[16], h2v[16];
  #pragma unroll
  for (int k = 0; k < 16; ++k){ h1v[k]=0.f; h2v[k]=0.f; }
  float h1own = 0.f, h2own = 0.f;

  for (int t = 0; t < Tn; ++t){
    if ((t & 63) == 0 && t){
      int c = t >> 6;
      if (c < 3){
        const float* gs = gsrc + (c+1)*6144;
        for (int it = 0; it < 24; ++it)
          gload16(gs + it*256 + lane*4, &gib[(c+1)&1][it*256]);
        asm volatile("s_waitcnt vmcnt(24)" ::: "memory");
      } else {
        asm volatile("s_waitcnt vmcnt(0)" ::: "memory");
      }
    }
    const float* gt = &gib[(t>>6)&1][(t&63)*96];
    float c_r = gt[h], c_z = gt[32+h], c_n = gt[64+h];
    float pr, pz, pn;
    DOT16(pr, h1v, a0h[0]); DOT16(pz, h1v, a0h[1]); DOT16(pn, h1v, a0h[2]);
    pr += __shfl_xor(pr,32); pz += __shfl_xor(pz,32); pn += __shfl_xor(pn,32);
    float r = fsig(c_r + pr + bh0r);
    float z = fsig(c_z + pz + bh0z);
    float nn = ftanh(c_n + r*(pn + bh0n));
    float hn1 = nn + z*(h1own - nn);
    h1own = hn1;
    h1arr[h] = hn1;
    *(float4*)&h1v[0]  = *(const float4*)&h1arr[ko+0];
    *(float4*)&h1v[4]  = *(const float4*)&h1arr[ko+4];
    *(float4*)&h1v[8]  = *(const float4*)&h1arr[ko+8];
    *(float4*)&h1v[12] = *(const float4*)&h1arr[ko+12];
    float ur, uz, ui, vr, vz, vh;
    DOT16(ur, h1v, a1i[0]); DOT16(uz, h1v, a1i[1]); DOT16(ui, h1v, a1i[2]);
    DOT16(vr, h2v, a1h[0]); DOT16(vz, h2v, a1h[1]); DOT16(vh, h2v, a1h[2]);
    float qr = ur+vr, qz = uz+vz;
    qr += __shfl_xor(qr,32); qz += __shfl_xor(qz,32);
    ui += __shfl_xor(ui,32); vh += __shfl_xor(vh,32);
    float r1 = fsig(qr + b1r);
    float z1 = fsig(qz + b1z);
    float n1 = ftanh(ui + bi1n + r1*(vh + bh1n));
    float hn2 = n1 + z1*(h2own - n1);
    h2own = hn2;
    h2arr[h] = hn2;
    *(float4*)&h2v[0]  = *(const float4*)&h2arr[ko+0];
    *(float4*)&h2v[4]  = *(const float4*)&h2arr[ko+4];
    *(float4*)&h2v[8]  = *(const float4*)&h2arr[ko+8];
    *(float4*)&h2v[12] = *(const float4*)&h2arr[ko+12];
    float x1v[16];
    #pragma unroll
    for (int k = 0; k < 16; ++k) x1v[k] = h1v[k] + h2v[k];
    float s;
    DOT16(s, x1v, afc);
    s += __shfl_xor(s,32);
    if (q == 0) bmA[(b*Tn + t)*32 + h] = fsig(s);
  }
}

// ---------- kP: fused low/high fc_in + PReLU + gi projections (replaces k4,k4b,k4c).
// block: 32 bt rows, 256 threads. xb: [32][292] (lpi 0..255 | bm 256..287). mb: [32][100] mid.
__global__ __launch_bounds__(256) void kP(const float* __restrict__ lpi,
    const float* __restrict__ bmA,
    const float* __restrict__ wlo, const float* __restrict__ plo,
    const float* __restrict__ whi, const float* __restrict__ phi,
    const float* __restrict__ wBT, const float* __restrict__ bB,
    float* __restrict__ giL, float* __restrict__ giH)
{
  __shared__ float xb[32*292];
  __shared__ float mb[32*100];
  const int tid = threadIdx.x;
  const int b = blockIdx.x >> 3;
  const int t0 = (blockIdx.x & 7)*32;
  const int bt0 = b*256 + t0;
  #pragma unroll
  for (int j = 0; j < 8; ++j){
    int idx = j*256 + tid;
    int row = idx >> 6, c4 = idx & 63;
    float4 v = *(const float4*)&lpi[(bt0 + row)*256 + c4*4];
    *(float4*)&xb[row*292 + c4*4] = v;
  }
  {
    int row = tid >> 3, c4 = tid & 7;
    float4 v = *(const float4*)&bmA[(bt0 + row)*32 + c4*4];
    *(float4*)&xb[row*292 + 256 + c4*4] = v;
  }
  __syncthreads();
  const int og = tid >> 3, btg = tid & 7;
  // ---- step A: mid = PReLU(fc_in)  (low: 64 outs, K=160; high: 32 outs, K=80)
  if (og < 16){
    float acc[4][4];
    #pragma unroll
    for (int bj = 0; bj < 4; ++bj){ acc[bj][0]=0.f; acc[bj][1]=0.f; acc[bj][2]=0.f; acc[bj][3]=0.f; }
    for (int kq = 0; kq < 40; ++kq){
      int k0_ = kq*4;
      int kk = (k0_ < 128) ? k0_ : k0_ + 128;
      float4 wv[4];
      #pragma unroll
      for (int i = 0; i < 4; ++i) wv[i] = *(const float4*)&wlo[(k0_+i)*64 + og*4];
      #pragma unroll
      for (int bj = 0; bj < 4; ++bj){
        float4 xv = *(const float4*)&xb[(btg + 8*bj)*292 + kk];
        FMA44(acc[bj], xv, wv);
      }
    }
    const float a = plo[0];
    #pragma unroll
    for (int bj = 0; bj < 4; ++bj){
      float4 m;
      m.x = acc[bj][0] >= 0.f ? acc[bj][0] : a*acc[bj][0];
      m.y = acc[bj][1] >= 0.f ? acc[bj][1] : a*acc[bj][1];
      m.z = acc[bj][2] >= 0.f ? acc[bj][2] : a*acc[bj][2];
      m.w = acc[bj][3] >= 0.f ? acc[bj][3] : a*acc[bj][3];
      *(float4*)&mb[(btg + 8*bj)*100 + og*4] = m;
    }
  } else if (og < 24){
    int o0 = (og - 16)*4;
    int g = o0 >> 4, r0 = o0 & 15;
    int xoff = 128 + g*80;
    float acc[4][4];
    #pragma unroll
    for (int bj = 0; bj < 4; ++bj){ acc[bj][0]=0.f; acc[bj][1]=0.f; acc[bj][2]=0.f; acc[bj][3]=0.f; }
    for (int kq = 0; kq < 20; ++kq){
      int k0_ = kq*4;
      float4 wv[4];
      #pragma unroll
      for (int i = 0; i < 4; ++i) wv[i] = *(const float4*)&whi[(g*80 + k0_ + i)*16 + r0];
      #pragma unroll
      for (int bj = 0; bj < 4; ++bj){
        float4 xv = *(const float4*)&xb[(btg + 8*bj)*292 + xoff + k0_];
        FMA44(acc[bj], xv, wv);
      }
    }
    const float a = phi[0];
    #pragma unroll
    for (int bj = 0; bj < 4; ++bj){
      float4 m;
      m.x = acc[bj][0] >= 0.f ? acc[bj][0] : a*acc[bj][0];
      m.y = acc[bj][1] >= 0.f ? acc[bj][1] : a*acc[bj][1];
      m.z = acc[bj][2] >= 0.f ? acc[bj][2] : a*acc[bj][2];
      m.w = acc[bj][3] >= 0.f ? acc[bj][3] : a*acc[bj][3];
      *(float4*)&mb[(btg + 8*bj)*100 + 64 + o0] = m;
    }
  }
  __syncthreads();
  // ---- step B: giL[192] (K=32 per group) + giH[96] (K=16 per group)
  for (int og2 = og; og2 < 72; og2 += 32){
    int woff, kbase, K, obase, dstride;
    float* dst;
    float4 bias;
    if (og2 < 48){
      woff = og2*128; kbase = (og2 >= 24) ? 32 : 0; K = 32;
      obase = og2*4; dst = giL; dstride = 192;
      bias = *(const float4*)&bB[obase];
    } else {
      int oh = og2 - 48;
      woff = 6144 + oh*64;
      int o0 = oh*4; int g = o0/48;
      kbase = 64 + g*16; K = 16;
      obase = o0; dst = giH; dstride = 96;
      bias = *(const float4*)&bB[192 + o0];
    }
    float acc[4][4];
    #pragma unroll
    for (int bj = 0; bj < 4; ++bj){ acc[bj][0]=0.f; acc[bj][1]=0.f; acc[bj][2]=0.f; acc[bj][3]=0.f; }
    for (int kq = 0; kq < K/4; ++kq){
      float4 wv[4];
      #pragma unroll
      for (int i = 0; i < 4; ++i) wv[i] = *(const float4*)&wBT[woff + (kq*4 + i)*4];
      #pragma unroll
      for (int bj = 0; bj < 4; ++bj){
        float4 xv = *(const float4*)&mb[(btg + 8*bj)*100 + kbase + kq*4];
        FMA44(acc[bj], xv, wv);
      }
    }
    #pragma unroll
    for (int bj = 0; bj < 4; ++bj){
      int btl = btg + 8*bj;
      float4 o;
      o.x = acc[bj][0] + bias.x; o.y = acc[bj][1] + bias.y;
      o.z = acc[bj][2] + bias.z; o.w = acc[bj][3] + bias.w;
      *(float4*)&dst[(bt0 + btl)*dstride + obase] = o;
    }
  }
}

// ---------- k5: low grouped 2-layer GRU + shuffle. 2 waves (wave = group), raw barrier. (unchanged)
__global__ __launch_bounds__(128,1) void k5(const float* __restrict__ giL,
    const float* __restrict__ wih, const float* __restrict__ whh,
    const float* __restrict__ bih, const float* __restrict__ bhh,
    float* __restrict__ acc)
{
  const int tid = threadIdx.x;
  const int g = tid >> 6;
  const int lane = tid & 63;
  const int q = lane >> 5, h = lane & 31, ko = q*16;
  const int b = blockIdx.x;
  float a0h[3][16], a1i[3][16], a1h[3][16];
  #pragma unroll
  for (int gt_ = 0; gt_ < 3; ++gt_){
    const float* w0 = whh + (g*96 + gt_*32 + h)*32 + ko;
    const float* wi = wih + ((2+g)*96 + gt_*32 + h)*32 + ko;
    const float* wh = whh + ((2+g)*96 + gt_*32 + h)*32 + ko;
    #pragma unroll
    for (int k = 0; k < 16; ++k){
      int pk = (k < 8) ? 2*k : 2*(k-8)+1;
      a0h[gt_][k] = w0[pk];
      a1i[gt_][k] = wi[k];
      a1h[gt_][k] = wh[k];
    }
  }
  const float bh0r = bhh[g*96+h], bh0z = bhh[g*96+32+h], bh0n = bhh[g*96+64+h];
  const float b1r = bih[(2+g)*96+h] + bhh[(2+g)*96+h];
  const float b1z = bih[(2+g)*96+32+h] + bhh[(2+g)*96+32+h];
  const float bi1n = bih[(2+g)*96+64+h], bh1n = bhh[(2+g)*96+64+h];

  __shared__ __attribute__((aligned(16))) float gib[2][2][3072];
  __shared__ __attribute__((aligned(16))) float ybuf[2][64];
  __shared__ __attribute__((aligned(16))) float h1l[2][32];
  const float* gsrc = giL + b*49152 + g*96;
  #pragma unroll
  for (int c0 = 0; c0 < 2; ++c0)
    for (int it = 0; it < 12; ++it){
      int i = it*64 + lane;
      int toff = i/24, c4 = i - toff*24;
      gload16(gsrc + (c0*32 + toff)*192 + c4*4, &gib[g][c0][it*256]);
    }
  asm volatile("s_waitcnt vmcnt(12)" ::: "memory");

  float h0v[16], h1v[16];
  #pragma unroll
  for (int k = 0; k < 16; ++k){ h0v[k]=0.f; h1v[k]=0.f; }
  float h0own = 0.f, h1own = 0.f;

  for (int t = 0; t < Tn; ++t){
    if ((t & 31) == 0 && t){
      int c = t >> 5;
      if (c < 7){
        for (int it = 0; it < 12; ++it){
          int i = it*64 + lane;
          int toff = i/24, c4 = i - toff*24;
          gload16(gsrc + ((c+1)*32 + toff)*192 + c4*4, &gib[g][(c+1)&1][it*256]);
        }
        asm volatile("s_waitcnt vmcnt(12)" ::: "memory");
      } else {
        asm volatile("s_waitcnt vmcnt(0)" ::: "memory");
      }
    }
    const float* gt = &gib[g][(t>>5)&1][(t&31)*96];
    float c_r = gt[h], c_z = gt[32+h], c_n = gt[64+h];
    float pr, pz, pn;
    DOT16(pr, h0v, a0h[0]); DOT16(pz, h0v, a0h[1]); DOT16(pn, h0v, a0h[2]);
    pr += __shfl_xor(pr,32); pz += __shfl_xor(pz,32); pn += __shfl_xor(pn,32);
    float r = fsig(c_r + pr + bh0r);
    float z = fsig(c_z + pz + bh0z);
    float nn = ftanh(c_n + r*(pn + bh0n));
    float hn0 = nn + z*(h0own - nn);
    h0own = hn0;
    ybuf[t&1][((h&1)<<5) + (g<<4) + (h>>1)] = hn0;
    asm volatile("s_waitcnt lgkmcnt(0)" ::: "memory");
    __builtin_amdgcn_sched_barrier(0);
    __builtin_amdgcn_s_barrier();
    __builtin_amdgcn_sched_barrier(0);
    const float* yb = ybuf[t&1];
    *(float4*)&h0v[0]  = *(const float4*)&yb[g*16 + (ko>>1)];
    *(float4*)&h0v[4]  = *(const float4*)&yb[g*16 + (ko>>1) + 4];
    *(float4*)&h0v[8]  = *(const float4*)&yb[32 + g*16 + (ko>>1)];
    *(float4*)&h0v[12] = *(const float4*)&yb[32 + g*16 + (ko>>1) + 4];
    float xv[16];
    *(float4*)&xv[0]  = *(const float4*)&yb[g*32 + ko + 0];
    *(float4*)&xv[4]  = *(const float4*)&yb[g*32 + ko + 4];
    *(float4*)&xv[8]  = *(const float4*)&yb[g*32 + ko + 8];
    *(float4*)&xv[12] = *(const float4*)&yb[g*32 + ko + 12];
    float yown = yb[g*32 + h];
    float ur, uz, ui, vr, vz, vh;
    DOT16(ur, xv, a1i[0]); DOT16(uz, xv, a1i[1]); DOT16(ui, xv, a1i[2]);
    DOT16(vr, h1v, a1h[0]); DOT16(vz, h1v, a1h[1]); DOT16(vh, h1v, a1h[2]);
    float qr = ur+vr, qz = uz+vz;
    qr += __shfl_xor(qr,32); qz += __shfl_xor(qz,32);
    ui += __shfl_xor(ui,32); vh += __shfl_xor(vh,32);
    float r1 = fsig(qr + b1r);
    float z1 = fsig(qz + b1z);
    float n1 = ftanh(ui + bi1n + r1*(vh + bh1n));
    float hn1 = n1 + z1*(h1own - n1);
    h1own = hn1;
    h1l[g][h] = hn1;
    *(float4*)&h1v[0]  = *(const float4*)&h1l[g][ko+0];
    *(float4*)&h1v[4]  = *(const float4*)&h1l[g][ko+4];
    *(float4*)&h1v[8]  = *(const float4*)&h1l[g][ko+8];
    *(float4*)&h1v[12] = *(const float4*)&h1l[g][ko+12];
    if (q == 0) acc[(t*Bn + b)*64 + g*32 + h] = yown + hn1;
  }
}

// ---------- k6: high grouped GRU (2 groups, H=16). 1 wave/batch, LDS gi chunks. (unchanged)
__global__ __launch_bounds__(64,1) void k6(const float* __restrict__ giH,
    const float* __restrict__ whh, const float* __restrict__ bhh,
    float* __restrict__ dfh)
{
  const int lane = threadIdx.x;
  const int g = lane >> 5, q = (lane >> 4) & 1, h = lane & 15, ko = q*8;
  const int b = blockIdx.x;
  float ah[3][8];
  #pragma unroll
  for (int gt_ = 0; gt_ < 3; ++gt_){
    const float* w = whh + (g*48 + gt_*16 + h)*16 + ko;
    #pragma unroll
    for (int k = 0; k < 8; ++k) ah[gt_][k] = w[k];
  }
  const float bhr = bhh[g*48+h], bhz = bhh[g*48+16+h], bhn = bhh[g*48+32+h];
  __shared__ __attribute__((aligned(16))) float gib[2][6144];
  __shared__ __attribute__((aligned(16))) float harr[32];
  const float* gsrc = giH + b*24576;
  #pragma unroll
  for (int c0 = 0; c0 < 2; ++c0)
    for (int it = 0; it < 24; ++it)
      gload16(gsrc + c0*6144 + it*256 + lane*4, &gib[c0][it*256]);
  asm volatile("s_waitcnt vmcnt(24)" ::: "memory");

  float hv[8];
  #pragma unroll
  for (int k = 0; k < 8; ++k) hv[k] = 0.f;
  float hown = 0.f;

  for (int t = 0; t < Tn; ++t){
    if ((t & 63) == 0 && t){
      int c = t >> 6;
      if (c < 3){
        const float* gs = gsrc + (c+1)*6144;
        for (int it = 0; it < 24; ++it)
          gload16(gs + it*256 + lane*4, &gib[(c+1)&1][it*256]);
        asm volatile("s_waitcnt vmcnt(24)" ::: "memory");
      } else {
        asm volatile("s_waitcnt vmcnt(0)" ::: "memory");
      }
    }
    const float* gt = &gib[(t>>6)&1][(t&63)*96 + g*48];
    float c_r = gt[h], c_z = gt[16+h], c_n = gt[32+h];
    float pr, pz, pn;
    DOT8(pr, hv, ah[0]); DOT8(pz, hv, ah[1]); DOT8(pn, hv, ah[2]);
    pr += __shfl_xor(pr,16); pz += __shfl_xor(pz,16); pn += __shfl_xor(pn,16);
    float r = fsig(c_r + pr + bhr);
    float z = fsig(c_z + pz + bhz);
    float nn = ftanh(c_n + r*(pn + bhn));
    float hn = nn + z*(hown - nn);
    hown = hn;
    harr[g*16 + h] = hn;
    *(float4*)&hv[0] = *(const float4*)&harr[g*16 + ko + 0];
    *(float4*)&hv[4] = *(const float4*)&harr[g*16 + ko + 4];
    if (q == 0) dfh[(t*Bn + b)*32 + g*16 + h] = hn;
  }
}

// ---------- k7: full_mask from bmA + mask_low/high fc + final fusion (unchanged)
__global__ __launch_bounds__(256) void k7(const float* __restrict__ acc,
    const float* __restrict__ dfh, const float* __restrict__ bmA,
    const float* __restrict__ wlo, const float* __restrict__ whi,
    const float* __restrict__ spec, float* __restrict__ out)
{
  __shared__ float accs[32][65];
  __shared__ float dfhs[32][33];
  __shared__ float bmt[32][33];
  __shared__ float mlds[128][32];
  __shared__ float mhds[128][32];
  __shared__ float frcs[257];
  __shared__ int   ibds[257];
  const int tid = threadIdx.x;
  const int b  = blockIdx.x >> 3;
  const int t0 = (blockIdx.x & 7) * 32;
  for (int idx = tid; idx < 32*16; idx += 256){
    int tl = idx >> 4, c4 = (idx & 15)*4;
    float4 v = *(const float4*)&acc[((t0 + tl)*Bn + b)*64 + c4];
    accs[tl][c4] = v.x; accs[tl][c4+1] = v.y; accs[tl][c4+2] = v.z; accs[tl][c4+3] = v.w;
  }
  for (int idx = tid; idx < 32*8; idx += 256){
    int tl = idx >> 3, c4 = (idx & 7)*4;
    float4 v = *(const float4*)&dfh[((t0 + tl)*Bn + b)*32 + c4];
    dfhs[tl][c4] = v.x; dfhs[tl][c4+1] = v.y; dfhs[tl][c4+2] = v.z; dfhs[tl][c4+3] = v.w;
    float4 u = *(const float4*)&bmA[(b*Tn + t0 + tl)*32 + c4];
    bmt[tl][c4] = u.x; bmt[tl][c4+1] = u.y; bmt[tl][c4+2] = u.z; bmt[tl][c4+3] = u.w;
  }
  for (int f = tid; f < 257; f += 256){
    int i = 0;
    #pragma unroll
    for (int k = 1; k < 31; ++k) if (f >= EB[k]) i = k;
    ibds[f] = i;
    frcs[f] = (f < 256) ? (float)(f - EB[i]) / (float)(EB[i+1] - EB[i]) : 0.f;
  }
  __syncthreads();
  const int tl = tid & 31, fo = tid >> 5;
  {
    float p[16];
    #pragma unroll
    for (int j = 0; j < 16; ++j) p[j] = 0.f;
    for (int i = 0; i < 64; ++i){
      float a = accs[tl][i];
      const float4* wr = (const float4*)&wlo[i*128 + fo*16];
      #pragma unroll
      for (int j4 = 0; j4 < 4; ++j4){
        float4 wv = wr[j4];
        p[j4*4+0] = fmaf(a, wv.x, p[j4*4+0]);
        p[j4*4+1] = fmaf(a, wv.y, p[j4*4+1]);
        p[j4*4+2] = fmaf(a, wv.z, p[j4*4+2]);
        p[j4*4+3] = fmaf(a, wv.w, p[j4*4+3]);
      }
    }
    #pragma unroll
    for (int j = 0; j < 16; ++j) mlds[fo*16 + j][tl] = fsig(p[j]);
  }
  {
    float p[16];
    #pragma unroll
    for (int j = 0; j < 16; ++j) p[j] = 0.f;
    const int g = fo >> 2, ob = (fo & 3)*16;
    for (int i = 0; i < 16; ++i){
      float a = dfhs[tl][g*16 + i];
      const float4* wr = (const float4*)&whi[(g*16 + i)*64 + ob];
      #pragma unroll
      for (int j4 = 0; j4 < 4; ++j4){
        float4 wv = wr[j4];
        p[j4*4+0] = fmaf(a, wv.x, p[j4*4+0]);
        p[j4*4+1] = fmaf(a, wv.y, p[j4*4+1]);
        p[j4*4+2] = fmaf(a, wv.z, p[j4*4+2]);
        p[j4*4+3] = fmaf(a, wv.w, p[j4*4+3]);
      }
    }
    #pragma unroll
    for (int j = 0; j < 16; ++j) mhds[fo*16 + j][tl] = fsig(p[j]);
  }
  __syncthreads();
  float* out1 = out + 16842752;
  float* out2 = out + 2*16842752;
  float2* out3 = (float2*)(out + 3*16842752);
  const float2* sp2 = (const float2*)spec;
  for (int f = fo; f < 257; f += 8){
    int base = (b*257 + f)*Tn + t0 + tl;
    float full;
    if (f < 256){
      int i = ibds[f]; float fr = frcs[f];
      full = bmt[tl][i]*(1.f - fr) + bmt[tl][i+1]*fr;
    } else full = 0.f;
    float m = (f < 128) ? mlds[f][tl]*full
            : (f < 256 ? mhds[f-128][tl]*full : full);
    float2 s = sp2[base];
    float ox = s.x*full, oy = s.y*full;
    float sx = ox*m, sy = oy*m;
    out[base]  = full;
    out1[base] = m;
    out2[base] = sqrtf(sx*sx + sy*sy);
    out3[base] = make_float2(sx, sy);
  }
}

extern "C" void kernel_launch(void* const* d_in, const int* in_sizes, int n_in,
                              void* d_out, int out_size, void* d_ws, size_t ws_size,
                              hipStream_t stream){
  const float* mi   = (const float*)d_in[0];
  const float* spec = (const float*)d_in[1];
  const float* lpi  = (const float*)d_in[2];
  const float* s1w  = (const float*)d_in[5];
  const float* s1b  = (const float*)d_in[6];
  const float* wih0 = (const float*)d_in[7];
  const float* whh0 = (const float*)d_in[8];
  const float* bih0 = (const float*)d_in[9];
  const float* bhh0 = (const float*)d_in[10];
  const float* wih1 = (const float*)d_in[11];
  const float* whh1 = (const float*)d_in[12];
  const float* bih1 = (const float*)d_in[13];
  const float* bhh1 = (const float*)d_in[14];
  const float* fco  = (const float*)d_in[15];
  const float* filw = (const float*)d_in[16];
  const float* plo  = (const float*)d_in[17];
  const float* fihw = (const float*)d_in[18];
  const float* phi  = (const float*)d_in[19];
  const float* glw_ih = (const float*)d_in[20];
  const float* glw_hh = (const float*)d_in[21];
  const float* glb_ih = (const float*)d_in[22];
  const float* glb_hh = (const float*)d_in[23];
  const float* ghw_ih = (const float*)d_in[24];
  const float* ghw_hh = (const float*)d_in[25];
  const float* ghb_ih = (const float*)d_in[26];
  const float* ghb_hh = (const float*)d_in[27];
  const float* folw = (const float*)d_in[28];
  const float* fohw = (const float*)d_in[29];

  // big Gi scratch lives in d_out (fully overwritten by k7 at the end)
  float* outf = (float*)d_out;
  float* giL = outf;                      // [B][T][192] 12,582,912
  float* gi0 = outf + 12582912;           // [B][T][96]   6,291,456
  float* giH = outf + 18874368;           // [B][T][96]   6,291,456

  float* ws  = (float*)d_ws;
  float* wcT = ws;                        // 6144
  float* bc  = ws + 6144;                 // 96
  float* wBT = ws + 6240;                 // 7680
  float* bB  = ws + 13920;                // 288
  float* bmA = ws + 14336;                // [B,T,32]  2,097,152
  float* acc = ws + 2111488;              // [T,B,64]  4,194,304
  float* dfh = ws + 6305792;              // [T,B,32]  2,097,152
  float* out = (float*)d_out;

  k0<<<56, 256, 0, stream>>>(s1w, s1b, wih0, bih0, glw_ih, glb_ih, ghw_ih, ghb_ih,
                             wcT, bc, wBT, bB);
  k1<<<2048, 256, 0, stream>>>(mi, wcT, bc, gi0);
  k2<<<256, 64, 0, stream>>>(gi0, whh0, bhh0, wih1, whh1, bih1, bhh1, fco, bmA);
  kP<<<2048, 256, 0, stream>>>(lpi, bmA, filw, plo, fihw, phi, wBT, bB, giL, giH);
  k5<<<256, 128, 0, stream>>>(giL, glw_ih, glw_hh, glb_ih, glb_hh, acc);
  k6<<<256, 64, 0, stream>>>(giH, ghw_hh, ghb_hh, dfh);
  k7<<<2048, 256, 0, stream>>>(acc, dfh, bmA, folw, fohw, spec, out);
}

// Round 6
// 723.295 us; speedup vs baseline: 2.1598x; 1.0850x over previous
//
#include <hip/hip_runtime.h>
#include <math.h>

#define Bn 256
#define Tn 256

__constant__ int EB[32] = {0,3,5,8,10,13,15,18,22,25,29,33,38,42,48,53,59,66,73,80,89,97,107,117,128,140,153,167,183,199,216,256};

__device__ __forceinline__ float fsig(float x){ return __builtin_amdgcn_rcpf(1.f + __expf(-x)); }
__device__ __forceinline__ float ftanh(float x){ return 1.f - 2.f*__builtin_amdgcn_rcpf(1.f + __expf(2.f*x)); }

__device__ __forceinline__ void gload16(const float* g, float* l){
  __builtin_amdgcn_global_load_lds((const __attribute__((address_space(1))) void*)g,
                                   (__attribute__((address_space(3))) void*)l, 16, 0, 0);
}

#define KEEP(x) asm volatile("" : "+v"(x))

#define DOT16(res, X, W) do{ float _s0=0.f,_s1=0.f,_s2=0.f,_s3=0.f; \
  _Pragma("unroll") for (int _e=0;_e<4;++_e){ \
    _s0=fmaf((X)[_e],(W)[_e],_s0); _s1=fmaf((X)[4+_e],(W)[4+_e],_s1); \
    _s2=fmaf((X)[8+_e],(W)[8+_e],_s2); _s3=fmaf((X)[12+_e],(W)[12+_e],_s3);} \
  (res)=(_s0+_s1)+(_s2+_s3); }while(0)

#define DOT8(res, X, W) do{ float _s0=0.f,_s1=0.f; \
  _Pragma("unroll") for (int _e=0;_e<4;++_e){ \
    _s0=fmaf((X)[_e],(W)[_e],_s0); _s1=fmaf((X)[4+_e],(W)[4+_e],_s1);} \
  (res)=_s0+_s1; }while(0)

// acc[4 outs] += x(float4 over k) * w[4 k](float4 over outs)
#define FMA44(A, X, W) do{ \
  (A)[0]=fmaf((X).x,(W)[0].x,(A)[0]); (A)[1]=fmaf((X).x,(W)[0].y,(A)[1]); (A)[2]=fmaf((X).x,(W)[0].z,(A)[2]); (A)[3]=fmaf((X).x,(W)[0].w,(A)[3]); \
  (A)[0]=fmaf((X).y,(W)[1].x,(A)[0]); (A)[1]=fmaf((X).y,(W)[1].y,(A)[1]); (A)[2]=fmaf((X).y,(W)[1].z,(A)[2]); (A)[3]=fmaf((X).y,(W)[1].w,(A)[3]); \
  (A)[0]=fmaf((X).z,(W)[2].x,(A)[0]); (A)[1]=fmaf((X).z,(W)[2].y,(A)[1]); (A)[2]=fmaf((X).z,(W)[2].z,(A)[2]); (A)[3]=fmaf((X).z,(W)[2].w,(A)[3]); \
  (A)[0]=fmaf((X).w,(W)[3].x,(A)[0]); (A)[1]=fmaf((X).w,(W)[3].y,(A)[1]); (A)[2]=fmaf((X).w,(W)[3].z,(A)[2]); (A)[3]=fmaf((X).w,(W)[3].w,(A)[3]); \
}while(0)

// ---------- k0: weight prep (unchanged, verified)
__global__ __launch_bounds__(256) void k0(const float* __restrict__ wfc, const float* __restrict__ bfc,
    const float* __restrict__ wih0, const float* __restrict__ bih0,
    const float* __restrict__ glw_ih, const float* __restrict__ glb_ih,
    const float* __restrict__ ghw_ih, const float* __restrict__ ghb_ih,
    float* __restrict__ wcT, float* __restrict__ bc,
    float* __restrict__ wBT, float* __restrict__ bB){
  int i = blockIdx.x*256 + threadIdx.x;
  if (i < 6144){
    int k = i/96, o = i - (i/96)*96;
    float s = 0.f;
    #pragma unroll
    for (int kk = 0; kk < 32; ++kk) s = fmaf(wih0[o*32+kk], wfc[kk*64+k], s);
    wcT[i] = s;
  } else if (i < 6240){
    int o = i - 6144;
    float s = bih0[o];
    #pragma unroll
    for (int kk = 0; kk < 32; ++kk) s = fmaf(wih0[o*32+kk], bfc[kk], s);
    bc[o] = s;
  } else if (i < 13920){
    int j = i - 6240;
    if (j < 6144){
      int og = j >> 7, rem = j & 127, k = rem >> 2, jj = rem & 3;
      int o = og*4 + jj; int g = o/96, r = o - g*96;
      wBT[j] = glw_ih[(g*96 + r)*32 + k];
    } else {
      int j2 = j - 6144;
      int oh = j2 >> 6, rem = j2 & 63, k = rem >> 2, jj = rem & 3;
      int o = oh*4 + jj; int g = o/48, r = o - g*48;
      wBT[j] = ghw_ih[(g*48 + r)*16 + k];
    }
  } else if (i < 14208){
    int o = i - 13920;
    bB[o] = (o < 192) ? glb_ih[o] : ghb_ih[o - 192];
  }
}

// ---------- k1: gi0[b][t][96] (unchanged, verified)
__global__ __launch_bounds__(256) void k1(const float* __restrict__ mi,
    const float* __restrict__ wcT, const float* __restrict__ bc,
    float* __restrict__ gi0){
  __shared__ float mbuf[33*36];
  const int tid = threadIdx.x;
  const int b = blockIdx.x >> 3;
  const int t0 = (blockIdx.x & 7)*32;
  const int bt0 = b*256 + t0;
  for (int idx = tid; idx < 264; idx += 256){
    int row = idx >> 3, c4 = idx & 7;
    int r = t0 - 1 + row;
    float4 v = make_float4(0.f,0.f,0.f,0.f);
    if (r >= 0) v = *(const float4*)&mi[(b*256 + r)*32 + c4*4];
    *(float4*)&mbuf[row*36 + c4*4] = v;
  }
  __syncthreads();
  const int og = tid >> 3, btg = tid & 7;
  if (og >= 24) return;
  float acc[4][4];
  #pragma unroll
  for (int bj = 0; bj < 4; ++bj){ acc[bj][0]=0.f; acc[bj][1]=0.f; acc[bj][2]=0.f; acc[bj][3]=0.f; }
  for (int fq = 0; fq < 8; ++fq){
    float4 wvp[4], wvc[4];
    #pragma unroll
    for (int i = 0; i < 4; ++i){
      int f = fq*4 + i;
      wvp[i] = *(const float4*)&wcT[(2*f)*96 + og*4];
      wvc[i] = *(const float4*)&wcT[(2*f+1)*96 + og*4];
    }
    #pragma unroll
    for (int bj = 0; bj < 4; ++bj){
      int btl = btg + 8*bj;
      float4 xp = *(const float4*)&mbuf[btl*36 + fq*4];
      float4 xc = *(const float4*)&mbuf[(btl+1)*36 + fq*4];
      FMA44(acc[bj], xp, wvp);
      FMA44(acc[bj], xc, wvc);
    }
  }
  float4 bias = *(const float4*)&bc[og*4];
  #pragma unroll
  for (int bj = 0; bj < 4; ++bj){
    int btl = btg + 8*bj;
    float4 o;
    o.x = acc[bj][0] + bias.x; o.y = acc[bj][1] + bias.y;
    o.z = acc[bj][2] + bias.z; o.w = acc[bj][3] + bias.w;
    *(float4*)&gi0[(bt0 + btl)*96 + og*4] = o;
  }
}

// ---------- k2: stage1 double GRU + band-mask fc (unchanged from round 5 — verified via output 0)
__global__ __launch_bounds__(64,1) void k2(const float* __restrict__ gi0,
    const float* __restrict__ whh0, const float* __restrict__ bhh0,
    const float* __restrict__ wih1, const float* __restrict__ whh1,
    const float* __restrict__ bih1, const float* __restrict__ bhh1,
    const float* __restrict__ fco, float* __restrict__ bmA)
{
  const int lane = threadIdx.x;
  const int q = lane >> 5, h = lane & 31, ko = q*16;
  const int b = blockIdx.x;
  float a0h[3][16], a1i[3][16], a1h[3][16], afc[16];
  #pragma unroll
  for (int g = 0; g < 3; ++g){
    const float* w0 = whh0 + (g*32+h)*32 + ko;
    const float* wi = wih1 + (g*32+h)*32 + ko;
    const float* wh = whh1 + (g*32+h)*32 + ko;
    #pragma unroll
    for (int k = 0; k < 16; ++k){ a0h[g][k]=w0[k]; a1i[g][k]=wi[k]; a1h[g][k]=wh[k]; }
  }
  #pragma unroll
  for (int k = 0; k < 16; ++k) afc[k] = fco[(ko+k)*32 + h];
  #pragma unroll
  for (int g = 0; g < 3; ++g){
    #pragma unroll
    for (int k = 0; k < 16; ++k){ KEEP(a0h[g][k]); KEEP(a1i[g][k]); KEEP(a1h[g][k]); }
  }
  #pragma unroll
  for (int k = 0; k < 16; ++k) KEEP(afc[k]);
  const float bh0r = bhh0[h], bh0z = bhh0[32+h], bh0n = bhh0[64+h];
  const float b1r = bih1[h]+bhh1[h], b1z = bih1[32+h]+bhh1[32+h];
  const float bi1n = bih1[64+h], bh1n = bhh1[64+h];

  __shared__ __attribute__((aligned(16))) float gib[2][6144];
  __shared__ __attribute__((aligned(16))) float h1arr[32];
  __shared__ __attribute__((aligned(16))) float h2arr[32];
  const float* gsrc = gi0 + b*24576;
  #pragma unroll
  for (int c0 = 0; c0 < 2; ++c0)
    for (int it = 0; it < 24; ++it)
      gload16(gsrc + c0*6144 + it*256 + lane*4, &gib[c0][it*256]);
  asm volatile("s_waitcnt vmcnt(24)" ::: "memory");

  float h1v[16], h2v[16];
  #pragma unroll
  for (int k = 0; k < 16; ++k){ h1v[k]=0.f; h2v[k]=0.f; }
  float h1own = 0.f, h2own = 0.f;
  float c_r, c_z, c_n, p_r=0.f, p_z=0.f, p_n=0.f;

  for (int t = 0; t < Tn; ++t){
    if ((t & 63) == 0){
      if (t){
        int c = t >> 6;
        if (c < 3){
          const float* gs = gsrc + (c+1)*6144;
          for (int it = 0; it < 24; ++it)
            gload16(gs + it*256 + lane*4, &gib[(c+1)&1][it*256]);
          asm volatile("s_waitcnt vmcnt(24)" ::: "memory");
        } else {
          asm volatile("s_waitcnt vmcnt(0)" ::: "memory");
        }
      }
      const float* gt = &gib[(t>>6)&1][(t&63)*96];
      c_r = gt[h]; c_z = gt[32+h]; c_n = gt[64+h];
    } else { c_r = p_r; c_z = p_z; c_n = p_n; }
    if ((t+1) & 63){
      const float* gn = &gib[((t+1)>>6)&1][((t+1)&63)*96];
      p_r = gn[h]; p_z = gn[32+h]; p_n = gn[64+h];
    }
    float pr, pz, pn;
    DOT16(pr, h1v, a0h[0]); DOT16(pz, h1v, a0h[1]); DOT16(pn, h1v, a0h[2]);
    pr += __shfl_xor(pr,32); pz += __shfl_xor(pz,32); pn += __shfl_xor(pn,32);
    float r = fsig(c_r + pr + bh0r);
    float z = fsig(c_z + pz + bh0z);
    float nn = ftanh(c_n + r*(pn + bh0n));
    float hn1 = nn + z*(h1own - nn);
    h1own = hn1;
    h1arr[h] = hn1;
    *(float4*)&h1v[0]  = *(const float4*)&h1arr[ko+0];
    *(float4*)&h1v[4]  = *(const float4*)&h1arr[ko+4];
    *(float4*)&h1v[8]  = *(const float4*)&h1arr[ko+8];
    *(float4*)&h1v[12] = *(const float4*)&h1arr[ko+12];
    float ur, uz, ui, vr, vz, vh;
    DOT16(ur, h1v, a1i[0]); DOT16(uz, h1v, a1i[1]); DOT16(ui, h1v, a1i[2]);
    DOT16(vr, h2v, a1h[0]); DOT16(vz, h2v, a1h[1]); DOT16(vh, h2v, a1h[2]);
    float qr = ur+vr, qz = uz+vz;
    qr += __shfl_xor(qr,32); qz += __shfl_xor(qz,32);
    ui += __shfl_xor(ui,32); vh += __shfl_xor(vh,32);
    float r1 = fsig(qr + b1r);
    float z1 = fsig(qz + b1z);
    float n1 = ftanh(ui + bi1n + r1*(vh + bh1n));
    float hn2 = n1 + z1*(h2own - n1);
    h2own = hn2;
    h2arr[h] = hn2;
    *(float4*)&h2v[0]  = *(const float4*)&h2arr[ko+0];
    *(float4*)&h2v[4]  = *(const float4*)&h2arr[ko+4];
    *(float4*)&h2v[8]  = *(const float4*)&h2arr[ko+8];
    *(float4*)&h2v[12] = *(const float4*)&h2arr[ko+12];
    float x1v[16];
    #pragma unroll
    for (int k = 0; k < 16; ++k) x1v[k] = h1v[k] + h2v[k];
    float s;
    DOT16(s, x1v, afc);
    s += __shfl_xor(s,32);
    if (q == 0) bmA[(b*Tn + t)*32 + h] = fsig(s);
  }
}

// ---------- kP: fused low/high fc_in + PReLU + gi projections (unchanged, verified)
__global__ __launch_bounds__(256) void kP(const float* __restrict__ lpi,
    const float* __restrict__ bmA,
    const float* __restrict__ wlo, const float* __restrict__ plo,
    const float* __restrict__ whi, const float* __restrict__ phi,
    const float* __restrict__ wBT, const float* __restrict__ bB,
    float* __restrict__ giL, float* __restrict__ giH)
{
  __shared__ float xb[32*292];
  __shared__ float mb[32*100];
  const int tid = threadIdx.x;
  const int b = blockIdx.x >> 3;
  const int t0 = (blockIdx.x & 7)*32;
  const int bt0 = b*256 + t0;
  #pragma unroll
  for (int j = 0; j < 8; ++j){
    int idx = j*256 + tid;
    int row = idx >> 6, c4 = idx & 63;
    float4 v = *(const float4*)&lpi[(bt0 + row)*256 + c4*4];
    *(float4*)&xb[row*292 + c4*4] = v;
  }
  {
    int row = tid >> 3, c4 = tid & 7;
    float4 v = *(const float4*)&bmA[(bt0 + row)*32 + c4*4];
    *(float4*)&xb[row*292 + 256 + c4*4] = v;
  }
  __syncthreads();
  const int og = tid >> 3, btg = tid & 7;
  if (og < 16){
    float acc[4][4];
    #pragma unroll
    for (int bj = 0; bj < 4; ++bj){ acc[bj][0]=0.f; acc[bj][1]=0.f; acc[bj][2]=0.f; acc[bj][3]=0.f; }
    for (int kq = 0; kq < 40; ++kq){
      int k0_ = kq*4;
      int kk = (k0_ < 128) ? k0_ : k0_ + 128;
      float4 wv[4];
      #pragma unroll
      for (int i = 0; i < 4; ++i) wv[i] = *(const float4*)&wlo[(k0_+i)*64 + og*4];
      #pragma unroll
      for (int bj = 0; bj < 4; ++bj){
        float4 xv = *(const float4*)&xb[(btg + 8*bj)*292 + kk];
        FMA44(acc[bj], xv, wv);
      }
    }
    const float a = plo[0];
    #pragma unroll
    for (int bj = 0; bj < 4; ++bj){
      float4 m;
      m.x = acc[bj][0] >= 0.f ? acc[bj][0] : a*acc[bj][0];
      m.y = acc[bj][1] >= 0.f ? acc[bj][1] : a*acc[bj][1];
      m.z = acc[bj][2] >= 0.f ? acc[bj][2] : a*acc[bj][2];
      m.w = acc[bj][3] >= 0.f ? acc[bj][3] : a*acc[bj][3];
      *(float4*)&mb[(btg + 8*bj)*100 + og*4] = m;
    }
  } else if (og < 24){
    int o0 = (og - 16)*4;
    int g = o0 >> 4, r0 = o0 & 15;
    int xoff = 128 + g*80;
    float acc[4][4];
    #pragma unroll
    for (int bj = 0; bj < 4; ++bj){ acc[bj][0]=0.f; acc[bj][1]=0.f; acc[bj][2]=0.f; acc[bj][3]=0.f; }
    for (int kq = 0; kq < 20; ++kq){
      int k0_ = kq*4;
      float4 wv[4];
      #pragma unroll
      for (int i = 0; i < 4; ++i) wv[i] = *(const float4*)&whi[(g*80 + k0_ + i)*16 + r0];
      #pragma unroll
      for (int bj = 0; bj < 4; ++bj){
        float4 xv = *(const float4*)&xb[(btg + 8*bj)*292 + xoff + k0_];
        FMA44(acc[bj], xv, wv);
      }
    }
    const float a = phi[0];
    #pragma unroll
    for (int bj = 0; bj < 4; ++bj){
      float4 m;
      m.x = acc[bj][0] >= 0.f ? acc[bj][0] : a*acc[bj][0];
      m.y = acc[bj][1] >= 0.f ? acc[bj][1] : a*acc[bj][1];
      m.z = acc[bj][2] >= 0.f ? acc[bj][2] : a*acc[bj][2];
      m.w = acc[bj][3] >= 0.f ? acc[bj][3] : a*acc[bj][3];
      *(float4*)&mb[(btg + 8*bj)*100 + 64 + o0] = m;
    }
  }
  __syncthreads();
  for (int og2 = og; og2 < 72; og2 += 32){
    int woff, kbase, K, obase, dstride;
    float* dst;
    float4 bias;
    if (og2 < 48){
      woff = og2*128; kbase = (og2 >= 24) ? 32 : 0; K = 32;
      obase = og2*4; dst = giL; dstride = 192;
      bias = *(const float4*)&bB[obase];
    } else {
      int oh = og2 - 48;
      woff = 6144 + oh*64;
      int o0 = oh*4; int g = o0/48;
      kbase = 64 + g*16; K = 16;
      obase = o0; dst = giH; dstride = 96;
      bias = *(const float4*)&bB[192 + o0];
    }
    float acc[4][4];
    #pragma unroll
    for (int bj = 0; bj < 4; ++bj){ acc[bj][0]=0.f; acc[bj][1]=0.f; acc[bj][2]=0.f; acc[bj][3]=0.f; }
    for (int kq = 0; kq < K/4; ++kq){
      float4 wv[4];
      #pragma unroll
      for (int i = 0; i < 4; ++i) wv[i] = *(const float4*)&wBT[woff + (kq*4 + i)*4];
      #pragma unroll
      for (int bj = 0; bj < 4; ++bj){
        float4 xv = *(const float4*)&mb[(btg + 8*bj)*100 + kbase + kq*4];
        FMA44(acc[bj], xv, wv);
      }
    }
    #pragma unroll
    for (int bj = 0; bj < 4; ++bj){
      int btl = btg + 8*bj;
      float4 o;
      o.x = acc[bj][0] + bias.x; o.y = acc[bj][1] + bias.y;
      o.z = acc[bj][2] + bias.z; o.w = acc[bj][3] + bias.w;
      *(float4*)&dst[(bt0 + btl)*dstride + obase] = o;
    }
  }
}

// ---------- k56: merged low GRU (blocks 0..255, 2 waves, __syncthreads exchange)
// and high GRU (blocks 256..383, 2 independent waves). Weights pinned in VGPRs.
__global__ __launch_bounds__(128,1) void k56(const float* __restrict__ giL,
    const float* __restrict__ giH,
    const float* __restrict__ wih, const float* __restrict__ whh,
    const float* __restrict__ bih, const float* __restrict__ bhh,
    const float* __restrict__ whhH, const float* __restrict__ bhhH,
    float* __restrict__ acc, float* __restrict__ dfh)
{
  __shared__ __attribute__((aligned(16))) float smem[12480];
  const int tid = threadIdx.x;
  if (blockIdx.x < 256){
    // ================= low path =================
    const int g = tid >> 6;
    const int lane = tid & 63;
    const int q = lane >> 5, h = lane & 31, ko = q*16;
    const int b = blockIdx.x;
    float a0h[3][16], a1i[3][16], a1h[3][16];
    #pragma unroll
    for (int gt_ = 0; gt_ < 3; ++gt_){
      const float* w0 = whh + (g*96 + gt_*32 + h)*32 + ko;
      const float* wi = wih + ((2+g)*96 + gt_*32 + h)*32 + ko;
      const float* wh = whh + ((2+g)*96 + gt_*32 + h)*32 + ko;
      #pragma unroll
      for (int k = 0; k < 16; ++k){
        int pk = (k < 8) ? 2*k : 2*(k-8)+1;
        a0h[gt_][k] = w0[pk];
        a1i[gt_][k] = wi[k];
        a1h[gt_][k] = wh[k];
      }
    }
    #pragma unroll
    for (int gt_ = 0; gt_ < 3; ++gt_){
      #pragma unroll
      for (int k = 0; k < 16; ++k){ KEEP(a0h[gt_][k]); KEEP(a1i[gt_][k]); KEEP(a1h[gt_][k]); }
    }
    const float bh0r = bhh[g*96+h], bh0z = bhh[g*96+32+h], bh0n = bhh[g*96+64+h];
    const float b1r = bih[(2+g)*96+h] + bhh[(2+g)*96+h];
    const float b1z = bih[(2+g)*96+32+h] + bhh[(2+g)*96+32+h];
    const float bi1n = bih[(2+g)*96+64+h], bh1n = bhh[(2+g)*96+64+h];

    float* gib  = smem + g*6144;        // [2][3072] per wave
    float* ybuf = smem + 12288;         // [2][64]
    float* h1l  = smem + 12416;         // [2][32]
    const float* gsrc = giL + b*49152 + g*96;
    #pragma unroll
    for (int c0 = 0; c0 < 2; ++c0)
      for (int it = 0; it < 12; ++it){
        int i = it*64 + lane;
        int toff = i/24, c4 = i - toff*24;
        gload16(gsrc + (c0*32 + toff)*192 + c4*4, &gib[c0*3072 + it*256]);
      }
    asm volatile("s_waitcnt vmcnt(12)" ::: "memory");

    float h0v[16], h1v[16];
    #pragma unroll
    for (int k = 0; k < 16; ++k){ h0v[k]=0.f; h1v[k]=0.f; }
    float h0own = 0.f, h1own = 0.f;
    float c_r, c_z, c_n, p_r=0.f, p_z=0.f, p_n=0.f;

    for (int t = 0; t < Tn; ++t){
      if ((t & 31) == 0){
        if (t){
          int c = t >> 5;
          if (c < 7){
            for (int it = 0; it < 12; ++it){
              int i = it*64 + lane;
              int toff = i/24, c4 = i - toff*24;
              gload16(gsrc + ((c+1)*32 + toff)*192 + c4*4, &gib[((c+1)&1)*3072 + it*256]);
            }
            asm volatile("s_waitcnt vmcnt(12)" ::: "memory");
          } else {
            asm volatile("s_waitcnt vmcnt(0)" ::: "memory");
          }
        }
        const float* gt = &gib[((t>>5)&1)*3072 + (t&31)*96];
        c_r = gt[h]; c_z = gt[32+h]; c_n = gt[64+h];
      } else { c_r = p_r; c_z = p_z; c_n = p_n; }
      if ((t+1) & 31){
        const float* gn = &gib[(((t+1)>>5)&1)*3072 + ((t+1)&31)*96];
        p_r = gn[h]; p_z = gn[32+h]; p_n = gn[64+h];
      }
      float pr, pz, pn;
      DOT16(pr, h0v, a0h[0]); DOT16(pz, h0v, a0h[1]); DOT16(pn, h0v, a0h[2]);
      pr += __shfl_xor(pr,32); pz += __shfl_xor(pz,32); pn += __shfl_xor(pn,32);
      float r = fsig(c_r + pr + bh0r);
      float z = fsig(c_z + pz + bh0z);
      float nn = ftanh(c_n + r*(pn + bh0n));
      float hn0 = nn + z*(h0own - nn);
      h0own = hn0;
      ybuf[(t&1)*64 + ((h&1)<<5) + (g<<4) + (h>>1)] = hn0;   // pre-shuffled position
      __syncthreads();    // full release/acquire fence — cross-wave exchange
      const float* yb = &ybuf[(t&1)*64];
      *(float4*)&h0v[0]  = *(const float4*)&yb[g*16 + (ko>>1)];
      *(float4*)&h0v[4]  = *(const float4*)&yb[g*16 + (ko>>1) + 4];
      *(float4*)&h0v[8]  = *(const float4*)&yb[32 + g*16 + (ko>>1)];
      *(float4*)&h0v[12] = *(const float4*)&yb[32 + g*16 + (ko>>1) + 4];
      float xv[16];
      *(float4*)&xv[0]  = *(const float4*)&yb[g*32 + ko + 0];
      *(float4*)&xv[4]  = *(const float4*)&yb[g*32 + ko + 4];
      *(float4*)&xv[8]  = *(const float4*)&yb[g*32 + ko + 8];
      *(float4*)&xv[12] = *(const float4*)&yb[g*32 + ko + 12];
      float yown = yb[g*32 + h];
      float ur, uz, ui, vr, vz, vh;
      DOT16(ur, xv, a1i[0]); DOT16(uz, xv, a1i[1]); DOT16(ui, xv, a1i[2]);
      DOT16(vr, h1v, a1h[0]); DOT16(vz, h1v, a1h[1]); DOT16(vh, h1v, a1h[2]);
      float qr = ur+vr, qz = uz+vz;
      qr += __shfl_xor(qr,32); qz += __shfl_xor(qz,32);
      ui += __shfl_xor(ui,32); vh += __shfl_xor(vh,32);
      float r1 = fsig(qr + b1r);
      float z1 = fsig(qz + b1z);
      float n1 = ftanh(ui + bi1n + r1*(vh + bh1n));
      float hn1 = n1 + z1*(h1own - n1);
      h1own = hn1;
      h1l[g*32 + h] = hn1;           // wave-private, redundant across q
      *(float4*)&h1v[0]  = *(const float4*)&h1l[g*32 + ko+0];
      *(float4*)&h1v[4]  = *(const float4*)&h1l[g*32 + ko+4];
      *(float4*)&h1v[8]  = *(const float4*)&h1l[g*32 + ko+8];
      *(float4*)&h1v[12] = *(const float4*)&h1l[g*32 + ko+12];
      if (q == 0) acc[(t*Bn + b)*64 + g*32 + h] = yown + hn1;
    }
  } else {
    // ================= high path: 2 independent chains, no barrier ====
    const int w = tid >> 6;
    const int lane = tid & 63;
    const int g = lane >> 5, q = (lane >> 4) & 1, h = lane & 15, ko = q*8;
    const int b = (blockIdx.x - 256)*2 + w;
    float ah[3][8];
    #pragma unroll
    for (int gt_ = 0; gt_ < 3; ++gt_){
      const float* wp = whhH + (g*48 + gt_*16 + h)*16 + ko;
      #pragma unroll
      for (int k = 0; k < 8; ++k) ah[gt_][k] = wp[k];
    }
    #pragma unroll
    for (int gt_ = 0; gt_ < 3; ++gt_){
      #pragma unroll
      for (int k = 0; k < 8; ++k) KEEP(ah[gt_][k]);
    }
    const float bhr = bhhH[g*48+h], bhz = bhhH[g*48+16+h], bhn = bhhH[g*48+32+h];
    float* gib  = smem + w*6144;        // [2][3072] per wave
    float* harr = smem + 12288 + w*32;
    const float* gsrc = giH + b*24576;
    #pragma unroll
    for (int c0 = 0; c0 < 2; ++c0)
      for (int it = 0; it < 12; ++it)
        gload16(gsrc + c0*3072 + it*256 + lane*4, &gib[c0*3072 + it*256]);
    asm volatile("s_waitcnt vmcnt(12)" ::: "memory");

    float hv[8];
    #pragma unroll
    for (int k = 0; k < 8; ++k) hv[k] = 0.f;
    float hown = 0.f;
    float c_r, c_z, c_n, p_r=0.f, p_z=0.f, p_n=0.f;

    for (int t = 0; t < Tn; ++t){
      if ((t & 31) == 0){
        if (t){
          int c = t >> 5;
          if (c < 7){
            const float* gs = gsrc + (c+1)*3072;
            for (int it = 0; it < 12; ++it)
              gload16(gs + it*256 + lane*4, &gib[((c+1)&1)*3072 + it*256]);
            asm volatile("s_waitcnt vmcnt(12)" ::: "memory");
          } else {
            asm volatile("s_waitcnt vmcnt(0)" ::: "memory");
          }
        }
        const float* gt = &gib[((t>>5)&1)*3072 + (t&31)*96 + g*48];
        c_r = gt[h]; c_z = gt[16+h]; c_n = gt[32+h];
      } else { c_r = p_r; c_z = p_z; c_n = p_n; }
      if ((t+1) & 31){
        const float* gn = &gib[(((t+1)>>5)&1)*3072 + ((t+1)&31)*96 + g*48];
        p_r = gn[h]; p_z = gn[16+h]; p_n = gn[32+h];
      }
      float pr, pz, pn;
      DOT8(pr, hv, ah[0]); DOT8(pz, hv, ah[1]); DOT8(pn, hv, ah[2]);
      pr += __shfl_xor(pr,16); pz += __shfl_xor(pz,16); pn += __shfl_xor(pn,16);
      float r = fsig(c_r + pr + bhr);
      float z = fsig(c_z + pz + bhz);
      float nn = ftanh(c_n + r*(pn + bhn));
      float hn = nn + z*(hown - nn);
      hown = hn;
      harr[g*16 + h] = hn;           // wave-private, redundant across q
      *(float4*)&hv[0] = *(const float4*)&harr[g*16 + ko + 0];
      *(float4*)&hv[4] = *(const float4*)&harr[g*16 + ko + 4];
      if (q == 0) dfh[(t*Bn + b)*32 + g*16 + h] = hn;
    }
  }
}

// ---------- k7: full_mask from bmA + mask fc + final fusion (unchanged, verified)
__global__ __launch_bounds__(256) void k7(const float* __restrict__ acc,
    const float* __restrict__ dfh, const float* __restrict__ bmA,
    const float* __restrict__ wlo, const float* __restrict__ whi,
    const float* __restrict__ spec, float* __restrict__ out)
{
  __shared__ float accs[32][65];
  __shared__ float dfhs[32][33];
  __shared__ float bmt[32][33];
  __shared__ float mlds[128][32];
  __shared__ float mhds[128][32];
  __shared__ float frcs[257];
  __shared__ int   ibds[257];
  const int tid = threadIdx.x;
  const int b  = blockIdx.x >> 3;
  const int t0 = (blockIdx.x & 7) * 32;
  for (int idx = tid; idx < 32*16; idx += 256){
    int tl = idx >> 4, c4 = (idx & 15)*4;
    float4 v = *(const float4*)&acc[((t0 + tl)*Bn + b)*64 + c4];
    accs[tl][c4] = v.x; accs[tl][c4+1] = v.y; accs[tl][c4+2] = v.z; accs[tl][c4+3] = v.w;
  }
  for (int idx = tid; idx < 32*8; idx += 256){
    int tl = idx >> 3, c4 = (idx & 7)*4;
    float4 v = *(const float4*)&dfh[((t0 + tl)*Bn + b)*32 + c4];
    dfhs[tl][c4] = v.x; dfhs[tl][c4+1] = v.y; dfhs[tl][c4+2] = v.z; dfhs[tl][c4+3] = v.w;
    float4 u = *(const float4*)&bmA[(b*Tn + t0 + tl)*32 + c4];
    bmt[tl][c4] = u.x; bmt[tl][c4+1] = u.y; bmt[tl][c4+2] = u.z; bmt[tl][c4+3] = u.w;
  }
  for (int f = tid; f < 257; f += 256){
    int i = 0;
    #pragma unroll
    for (int k = 1; k < 31; ++k) if (f >= EB[k]) i = k;
    ibds[f] = i;
    frcs[f] = (f < 256) ? (float)(f - EB[i]) / (float)(EB[i+1] - EB[i]) : 0.f;
  }
  __syncthreads();
  const int tl = tid & 31, fo = tid >> 5;
  {
    float p[16];
    #pragma unroll
    for (int j = 0; j < 16; ++j) p[j] = 0.f;
    for (int i = 0; i < 64; ++i){
      float a = accs[tl][i];
      const float4* wr = (const float4*)&wlo[i*128 + fo*16];
      #pragma unroll
      for (int j4 = 0; j4 < 4; ++j4){
        float4 wv = wr[j4];
        p[j4*4+0] = fmaf(a, wv.x, p[j4*4+0]);
        p[j4*4+1] = fmaf(a, wv.y, p[j4*4+1]);
        p[j4*4+2] = fmaf(a, wv.z, p[j4*4+2]);
        p[j4*4+3] = fmaf(a, wv.w, p[j4*4+3]);
      }
    }
    #pragma unroll
    for (int j = 0; j < 16; ++j) mlds[fo*16 + j][tl] = fsig(p[j]);
  }
  {
    float p[16];
    #pragma unroll
    for (int j = 0; j < 16; ++j) p[j] = 0.f;
    const int g = fo >> 2, ob = (fo & 3)*16;
    for (int i = 0; i < 16; ++i){
      float a = dfhs[tl][g*16 + i];
      const float4* wr = (const float4*)&whi[(g*16 + i)*64 + ob];
      #pragma unroll
      for (int j4 = 0; j4 < 4; ++j4){
        float4 wv = wr[j4];
        p[j4*4+0] = fmaf(a, wv.x, p[j4*4+0]);
        p[j4*4+1] = fmaf(a, wv.y, p[j4*4+1]);
        p[j4*4+2] = fmaf(a, wv.z, p[j4*4+2]);
        p[j4*4+3] = fmaf(a, wv.w, p[j4*4+3]);
      }
    }
    #pragma unroll
    for (int j = 0; j < 16; ++j) mhds[fo*16 + j][tl] = fsig(p[j]);
  }
  __syncthreads();
  float* out1 = out + 16842752;
  float* out2 = out + 2*16842752;
  float2* out3 = (float2*)(out + 3*16842752);
  const float2* sp2 = (const float2*)spec;
  for (int f = fo; f < 257; f += 8){
    int base = (b*257 + f)*Tn + t0 + tl;
    float full;
    if (f < 256){
      int i = ibds[f]; float fr = frcs[f];
      full = bmt[tl][i]*(1.f - fr) + bmt[tl][i+1]*fr;
    } else full = 0.f;
    float m = (f < 128) ? mlds[f][tl]*full
            : (f < 256 ? mhds[f-128][tl]*full : full);
    float2 s = sp2[base];
    float ox = s.x*full, oy = s.y*full;
    float sx = ox*m, sy = oy*m;
    out[base]  = full;
    out1[base] = m;
    out2[base] = sqrtf(sx*sx + sy*sy);
    out3[base] = make_float2(sx, sy);
  }
}

extern "C" void kernel_launch(void* const* d_in, const int* in_sizes, int n_in,
                              void* d_out, int out_size, void* d_ws, size_t ws_size,
                              hipStream_t stream){
  const float* mi   = (const float*)d_in[0];
  const float* spec = (const float*)d_in[1];
  const float* lpi  = (const float*)d_in[2];
  const float* s1w  = (const float*)d_in[5];
  const float* s1b  = (const float*)d_in[6];
  const float* wih0 = (const float*)d_in[7];
  const float* whh0 = (const float*)d_in[8];
  const float* bih0 = (const float*)d_in[9];
  const float* bhh0 = (const float*)d_in[10];
  const float* wih1 = (const float*)d_in[11];
  const float* whh1 = (const float*)d_in[12];
  const float* bih1 = (const float*)d_in[13];
  const float* bhh1 = (const float*)d_in[14];
  const float* fco  = (const float*)d_in[15];
  const float* filw = (const float*)d_in[16];
  const float* plo  = (const float*)d_in[17];
  const float* fihw = (const float*)d_in[18];
  const float* phi  = (const float*)d_in[19];
  const float* glw_ih = (const float*)d_in[20];
  const float* glw_hh = (const float*)d_in[21];
  const float* glb_ih = (const float*)d_in[22];
  const float* glb_hh = (const float*)d_in[23];
  const float* ghw_ih = (const float*)d_in[24];
  const float* ghw_hh = (const float*)d_in[25];
  const float* ghb_ih = (const float*)d_in[26];
  const float* ghb_hh = (const float*)d_in[27];
  const float* folw = (const float*)d_in[28];
  const float* fohw = (const float*)d_in[29];

  // big Gi scratch lives in d_out (fully overwritten by k7 at the end)
  float* outf = (float*)d_out;
  float* giL = outf;                      // [B][T][192] 12,582,912
  float* gi0 = outf + 12582912;           // [B][T][96]   6,291,456
  float* giH = outf + 18874368;           // [B][T][96]   6,291,456

  float* ws  = (float*)d_ws;
  float* wcT = ws;                        // 6144
  float* bc  = ws + 6144;                 // 96
  float* wBT = ws + 6240;                 // 7680
  float* bB  = ws + 13920;                // 288
  float* bmA = ws + 14336;                // [B,T,32]  2,097,152
  float* acc = ws + 2111488;              // [T,B,64]  4,194,304
  float* dfh = ws + 6305792;              // [T,B,32]  2,097,152
  float* out = (float*)d_out;

  k0<<<56, 256, 0, stream>>>(s1w, s1b, wih0, bih0, glw_ih, glb_ih, ghw_ih, ghb_ih,
                             wcT, bc, wBT, bB);
  k1<<<2048, 256, 0, stream>>>(mi, wcT, bc, gi0);
  k2<<<256, 64, 0, stream>>>(gi0, whh0, bhh0, wih1, whh1, bih1, bhh1, fco, bmA);
  kP<<<2048, 256, 0, stream>>>(lpi, bmA, filw, plo, fihw, phi, wBT, bB, giL, giH);
  k56<<<384, 128, 0, stream>>>(giL, giH, glw_ih, glw_hh, glb_ih, glb_hh,
                               ghw_hh, ghb_hh, acc, dfh);
  k7<<<2048, 256, 0, stream>>>(acc, dfh, bmA, folw, fohw, spec, out);
}